// Round 1
// baseline (440.103 us; speedup 1.0000x reference)
//
#include <hip/hip_runtime.h>

typedef unsigned short u16;
typedef __bf16 bf16x8 __attribute__((ext_vector_type(8)));
typedef float f32x4 __attribute__((ext_vector_type(4)));
typedef u16 u16x4 __attribute__((ext_vector_type(4)));

#define L2E 1.4426950408889634f

static __device__ __forceinline__ u16 f2bf(float f) {
  __bf16 h = (__bf16)f;
  return __builtin_bit_cast(u16, h);
}

static __device__ __forceinline__ void gl_lds16(const void* g, void* l) {
  __builtin_amdgcn_global_load_lds(
      (const __attribute__((address_space(1))) unsigned int*)g,
      (__attribute__((address_space(3))) unsigned int*)l, 16, 0, 0);
}

// ---------------------------------------------------------------------------
// fp32 -> bf16 elementwise convert (vectorized x4)
// ---------------------------------------------------------------------------
__global__ void k_cvt(const float* __restrict__ in, u16* __restrict__ out, int n4) {
  int i = blockIdx.x * 256 + threadIdx.x;
  if (i < n4) {
    f32x4 f = ((const f32x4*)in)[i];
    u16x4 u = { f2bf(f[0]), f2bf(f[1]), f2bf(f[2]), f2bf(f[3]) };
    ((u16x4*)out)[i] = u;
  }
}

// ---------------------------------------------------------------------------
// fp32 [R][C] -> bf16 [C][R] transpose+convert. block (32,8), grid (C/32,R/32)
// ---------------------------------------------------------------------------
__global__ void k_transpose_cvt(const float* __restrict__ in, u16* __restrict__ out,
                                int R, int C) {
  __shared__ float tile[32][33];
  const int c0 = blockIdx.x * 32, r0 = blockIdx.y * 32;
  const int tx = threadIdx.x, ty = threadIdx.y;
#pragma unroll
  for (int i = 0; i < 4; ++i)
    tile[ty + i * 8][tx] = in[(size_t)(r0 + ty + i * 8) * C + c0 + tx];
  __syncthreads();
#pragma unroll
  for (int i = 0; i < 4; ++i)
    out[(size_t)(c0 + ty + i * 8) * R + r0 + tx] = f2bf(tile[tx][ty + i * 8]);
}

// ---------------------------------------------------------------------------
// bf16 V [BH][4096][64] -> Vt [BH][64][4096]. block (32,8), grid (2,128,24)
// ---------------------------------------------------------------------------
__global__ void k_transpose_v(const u16* __restrict__ V, u16* __restrict__ Vt) {
  __shared__ u16 tile[32][33];
  const int bh = blockIdx.z;
  const int d0 = blockIdx.x * 32, t0 = blockIdx.y * 32;
  const int tx = threadIdx.x, ty = threadIdx.y;
#pragma unroll
  for (int i = 0; i < 4; ++i)
    tile[ty + i * 8][tx] = V[((size_t)bh * 4096 + t0 + ty + i * 8) * 64 + d0 + tx];
  __syncthreads();
#pragma unroll
  for (int i = 0; i < 4; ++i)
    Vt[((size_t)bh * 64 + d0 + ty + i * 8) * 4096 + t0 + tx] = tile[tx][ty + i * 8];
}

// ---------------------------------------------------------------------------
// Shared GEMM mainloop: C[128x128] = A[M][K] * Bt[N][K]^T, bf16, BK=64.
// 256 threads = 4 waves (2x2), each wave 64x64 = 4x4 fragments of 16x16.
// LDS tiles staged with global_load_lds(16B), source pre-swizzled so that
// XOR-swizzled ds_read_b128 fragment reads are bank-conflict-light.
// swizzle: byte ^= ((row&7)<<4) within the 128-byte row.
// ---------------------------------------------------------------------------
static __device__ __forceinline__ void gemm_core(const u16* __restrict__ Ag,
                                                 const u16* __restrict__ Btg,
                                                 int K, int m0, int n0,
                                                 u16* As, u16* Bs,
                                                 f32x4 acc[4][4]) {
  const int tid = threadIdx.x;
  const int lane = tid & 63;
  const int wid = tid >> 6;
  const int wm = wid >> 1, wn = wid & 1;
  const int l16 = lane & 15, lg = lane >> 4;

  for (int kt = 0; kt < K; kt += 64) {
    __syncthreads();  // previous iteration's LDS reads complete
#pragma unroll
    for (int i = 0; i < 4; ++i) {
      int chunk = i * 256 + tid;
      int row = chunk >> 3;
      int lcb = ((chunk & 7) << 4) ^ ((row & 7) << 4);
      gl_lds16(Ag + (size_t)(m0 + row) * K + kt + (lcb >> 1),
               As + ((i * 256 + wid * 64) << 3));
    }
#pragma unroll
    for (int i = 0; i < 4; ++i) {
      int chunk = i * 256 + tid;
      int row = chunk >> 3;
      int lcb = ((chunk & 7) << 4) ^ ((row & 7) << 4);
      gl_lds16(Btg + (size_t)(n0 + row) * K + kt + (lcb >> 1),
               Bs + ((i * 256 + wid * 64) << 3));
    }
    __syncthreads();  // staging complete (vmcnt drained by barrier)

#pragma unroll
    for (int ks = 0; ks < 2; ++ks) {
      bf16x8 af[4], bfr[4];
#pragma unroll
      for (int mi = 0; mi < 4; ++mi) {
        int row = wm * 64 + mi * 16 + l16;
        int off = row * 128 + ((ks * 64 + (lg << 4)) ^ ((row & 7) << 4));
        af[mi] = *(const bf16x8*)((const char*)As + off);
      }
#pragma unroll
      for (int ni = 0; ni < 4; ++ni) {
        int row = wn * 64 + ni * 16 + l16;
        int off = row * 128 + ((ks * 64 + (lg << 4)) ^ ((row & 7) << 4));
        bfr[ni] = *(const bf16x8*)((const char*)Bs + off);
      }
#pragma unroll
      for (int mi = 0; mi < 4; ++mi)
#pragma unroll
        for (int ni = 0; ni < 4; ++ni)
          acc[mi][ni] = __builtin_amdgcn_mfma_f32_16x16x32_bf16(
              af[mi], bfr[ni], acc[mi][ni], 0, 0, 0);
    }
  }
}

// ---------------------------------------------------------------------------
// GEMM1: Xbf[8192][768] * WqkvT[2304][768]^T + bqkv -> scatter Q,K,V [BH][T][64]
// grid (18, 64), 256 threads
// ---------------------------------------------------------------------------
__global__ __launch_bounds__(256) void k_gemm_qkv(
    const u16* __restrict__ A, const u16* __restrict__ Bt,
    const float* __restrict__ bias, u16* __restrict__ Q, u16* __restrict__ Kb,
    u16* __restrict__ V) {
  __shared__ __align__(16) u16 As[128 * 64];
  __shared__ __align__(16) u16 Bs[128 * 64];
  const int m0 = blockIdx.y * 128, n0 = blockIdx.x * 128;
  const f32x4 fz = {0.f, 0.f, 0.f, 0.f};
  f32x4 acc[4][4];
#pragma unroll
  for (int mi = 0; mi < 4; ++mi)
#pragma unroll
    for (int ni = 0; ni < 4; ++ni) acc[mi][ni] = fz;

  gemm_core(A, Bt, 768, m0, n0, As, Bs, acc);

  const int tid = threadIdx.x, lane = tid & 63, wid = tid >> 6;
  const int wm = wid >> 1, wn = wid & 1, l16 = lane & 15, lg = lane >> 4;
#pragma unroll
  for (int mi = 0; mi < 4; ++mi)
#pragma unroll
    for (int ni = 0; ni < 4; ++ni) {
      int n = n0 + wn * 64 + ni * 16 + l16;
      float bi = bias[n];
      int h = n / 192;
      int rr = n - h * 192;
#pragma unroll
      for (int r = 0; r < 4; ++r) {
        int m = m0 + wm * 64 + mi * 16 + lg * 4 + r;
        int b = m >> 12, t = m & 4095;
        float v = acc[mi][ni][r] + bi;
        size_t base = ((size_t)(b * 12 + h) * 4096 + t) * 64;
        u16 bv = f2bf(v);
        if (rr < 64)
          Q[base + rr] = bv;
        else if (rr < 128)
          Kb[base + rr - 64] = bv;
        else
          V[base + rr - 128] = bv;
      }
    }
}

// ---------------------------------------------------------------------------
// GEMM2: O[8192][768] * WprojT[768][768]^T + bproj -> out fp32
// grid (6, 64), 256 threads
// ---------------------------------------------------------------------------
__global__ __launch_bounds__(256) void k_gemm_proj(
    const u16* __restrict__ A, const u16* __restrict__ Bt,
    const float* __restrict__ bias, float* __restrict__ out) {
  __shared__ __align__(16) u16 As[128 * 64];
  __shared__ __align__(16) u16 Bs[128 * 64];
  const int m0 = blockIdx.y * 128, n0 = blockIdx.x * 128;
  const f32x4 fz = {0.f, 0.f, 0.f, 0.f};
  f32x4 acc[4][4];
#pragma unroll
  for (int mi = 0; mi < 4; ++mi)
#pragma unroll
    for (int ni = 0; ni < 4; ++ni) acc[mi][ni] = fz;

  gemm_core(A, Bt, 768, m0, n0, As, Bs, acc);

  const int tid = threadIdx.x, lane = tid & 63, wid = tid >> 6;
  const int wm = wid >> 1, wn = wid & 1, l16 = lane & 15, lg = lane >> 4;
#pragma unroll
  for (int mi = 0; mi < 4; ++mi)
#pragma unroll
    for (int ni = 0; ni < 4; ++ni) {
      int n = n0 + wn * 64 + ni * 16 + l16;
      float bi = bias[n];
#pragma unroll
      for (int r = 0; r < 4; ++r) {
        int m = m0 + wm * 64 + mi * 16 + lg * 4 + r;
        out[(size_t)m * 768 + n] = acc[mi][ni][r] + bi;
      }
    }
}

// ---------------------------------------------------------------------------
// Flash attention, causal. grid (64, 24), 256 threads = 4 waves.
// Block: 64 q-rows (wave w handles rows q0+w*16..+15). KV tiles of 64.
// Q [BH][T][64], K [BH][T][64], Vt [BH][64][T], all bf16. O -> [B][T][768] bf16.
// ---------------------------------------------------------------------------
__global__ __launch_bounds__(256) void k_attn(const u16* __restrict__ Qg,
                                              const u16* __restrict__ Kg,
                                              const u16* __restrict__ Vtg,
                                              u16* __restrict__ Og) {
  __shared__ __align__(16) u16 Ks[64 * 64];
  __shared__ __align__(16) u16 Vs[64 * 64];  // [d][kpos] (transposed tile)
  __shared__ __align__(16) u16 Ps[4 * 16 * 64];
  const int qt = blockIdx.x;
  const int bh = blockIdx.y;
  const int tid = threadIdx.x;
  const int lane = tid & 63;
  const int wid = tid >> 6;
  const int l16 = lane & 15;
  const int lg = lane >> 4;
  const size_t qk_base = (size_t)bh * (4096 * 64);
  const int q0 = qt * 64 + wid * 16;

  // Q fragments live in registers (A-operand layout)
  bf16x8 aq[2];
#pragma unroll
  for (int ks = 0; ks < 2; ++ks)
    aq[ks] = *(const bf16x8*)(Qg + qk_base + (size_t)(q0 + l16) * 64 + ks * 32 + lg * 8);

  const f32x4 fz = {0.f, 0.f, 0.f, 0.f};
  f32x4 o[4] = {fz, fz, fz, fz};
  float mrun[4], lrun[4];
#pragma unroll
  for (int r = 0; r < 4; ++r) {
    mrun[r] = -3.0e38f;
    lrun[r] = 0.f;
  }
  u16* Psw = Ps + wid * 1024;

  for (int kt = 0; kt <= qt; ++kt) {
    __syncthreads();
    // stage K tile [64][64] and Vt tile [64][64], source pre-swizzled
#pragma unroll
    for (int i = 0; i < 2; ++i) {
      int chunk = i * 256 + tid;
      int row = chunk >> 3;
      int lcb = ((chunk & 7) << 4) ^ ((row & 7) << 4);
      gl_lds16(Kg + qk_base + (size_t)(kt * 64 + row) * 64 + (lcb >> 1),
               Ks + ((i * 256 + wid * 64) << 3));
    }
#pragma unroll
    for (int i = 0; i < 2; ++i) {
      int chunk = i * 256 + tid;
      int row = chunk >> 3;
      int lcb = ((chunk & 7) << 4) ^ ((row & 7) << 4);
      gl_lds16(Vtg + (size_t)(bh * 64 + row) * 4096 + kt * 64 + (lcb >> 1),
               Vs + ((i * 256 + wid * 64) << 3));
    }
    __syncthreads();

    // S = Q K^T  (C layout: row=lg*4+reg (q), col=l16 (+n*16) (kpos))
    f32x4 s[4];
#pragma unroll
    for (int n = 0; n < 4; ++n) {
      s[n] = fz;
#pragma unroll
      for (int ks = 0; ks < 2; ++ks) {
        int row = n * 16 + l16;
        int off = row * 128 + ((ks * 64 + (lg << 4)) ^ ((row & 7) << 4));
        bf16x8 bk = *(const bf16x8*)((const char*)Ks + off);
        s[n] = __builtin_amdgcn_mfma_f32_16x16x32_bf16(aq[ks], bk, s[n], 0, 0, 0);
      }
    }

    // scale + causal mask
    float sv[4][4];
#pragma unroll
    for (int n = 0; n < 4; ++n) {
      int kpos = kt * 64 + n * 16 + l16;
#pragma unroll
      for (int r = 0; r < 4; ++r) {
        float v = s[n][r] * 0.125f;
        int qrow = q0 + lg * 4 + r;
        sv[n][r] = (kpos > qrow) ? -1e30f : v;
      }
    }

    // online softmax (wave-parallel: 16-lane-group shfl reductions)
    float alpha[4];
#pragma unroll
    for (int r = 0; r < 4; ++r) {
      float mx = fmaxf(fmaxf(sv[0][r], sv[1][r]), fmaxf(sv[2][r], sv[3][r]));
      mx = fmaxf(mx, __shfl_xor(mx, 1, 64));
      mx = fmaxf(mx, __shfl_xor(mx, 2, 64));
      mx = fmaxf(mx, __shfl_xor(mx, 4, 64));
      mx = fmaxf(mx, __shfl_xor(mx, 8, 64));
      float mnew = fmaxf(mrun[r], mx);
      alpha[r] = __builtin_exp2f((mrun[r] - mnew) * L2E);
      float rs = 0.f;
      int prow = lg * 4 + r;
#pragma unroll
      for (int n = 0; n < 4; ++n) {
        float p = __builtin_exp2f((sv[n][r] - mnew) * L2E);
        rs += p;
        int pb = prow * 128 + ((n * 32 + l16 * 2) ^ ((prow & 7) << 4));
        *(u16*)((char*)Psw + pb) = f2bf(p);
      }
      rs += __shfl_xor(rs, 1, 64);
      rs += __shfl_xor(rs, 2, 64);
      rs += __shfl_xor(rs, 4, 64);
      rs += __shfl_xor(rs, 8, 64);
      lrun[r] = lrun[r] * alpha[r] + rs;
      mrun[r] = mnew;
    }

    // rescale O accumulator
#pragma unroll
    for (int nd = 0; nd < 4; ++nd)
#pragma unroll
      for (int r = 0; r < 4; ++r) o[nd][r] *= alpha[r];

    // PV: A = P (from per-wave LDS), B = Vt tile
    bf16x8 pa[2];
#pragma unroll
    for (int ks = 0; ks < 2; ++ks) {
      int off = l16 * 128 + ((ks * 64 + (lg << 4)) ^ ((l16 & 7) << 4));
      pa[ks] = *(const bf16x8*)((const char*)Psw + off);
    }
#pragma unroll
    for (int nd = 0; nd < 4; ++nd) {
#pragma unroll
      for (int ks = 0; ks < 2; ++ks) {
        int row = nd * 16 + l16;
        int off = row * 128 + ((ks * 64 + (lg << 4)) ^ ((row & 7) << 4));
        bf16x8 bv = *(const bf16x8*)((const char*)Vs + off);
        o[nd] = __builtin_amdgcn_mfma_f32_16x16x32_bf16(pa[ks], bv, o[nd], 0, 0, 0);
      }
    }
  }

  // finalize + write O as [B][T][H*64] bf16
  const int b = bh / 12, h = bh - b * 12;
#pragma unroll
  for (int nd = 0; nd < 4; ++nd)
#pragma unroll
    for (int r = 0; r < 4; ++r) {
      int qrow = q0 + lg * 4 + r;
      float val = o[nd][r] / lrun[r];
      Og[((size_t)b * 4096 + qrow) * 768 + h * 64 + nd * 16 + l16] = f2bf(val);
    }
}

// ---------------------------------------------------------------------------
// launch
// ---------------------------------------------------------------------------
extern "C" void kernel_launch(void* const* d_in, const int* in_sizes, int n_in,
                              void* d_out, int out_size, void* d_ws, size_t ws_size,
                              hipStream_t stream) {
  const float* x = (const float*)d_in[0];
  const float* Wqkv = (const float*)d_in[1];
  const float* bqkv = (const float*)d_in[2];
  const float* Wproj = (const float*)d_in[3];
  const float* bproj = (const float*)d_in[4];
  float* out = (float*)d_out;

  char* ws = (char*)d_ws;
  // workspace layout (bytes), total ~80.2 MB
  u16* Xbf = (u16*)(ws + 0);            // 12,582,912
  u16* WqkvT = (u16*)(ws + 12582912);   //  3,538,944
  u16* WprojT = (u16*)(ws + 16121856);  //  1,179,648
  u16* Q = (u16*)(ws + 17301504);       // 12,582,912
  u16* K = (u16*)(ws + 29884416);       // 12,582,912
  u16* V = (u16*)(ws + 42467328);       // 12,582,912
  u16* Vt = (u16*)(ws + 55050240);      // 12,582,912
  u16* O = (u16*)(ws + 67633152);       // 12,582,912

  k_cvt<<<6144, 256, 0, stream>>>(x, Xbf, 1572864);
  k_transpose_cvt<<<dim3(72, 24), dim3(32, 8), 0, stream>>>(Wqkv, WqkvT, 768, 2304);
  k_transpose_cvt<<<dim3(24, 24), dim3(32, 8), 0, stream>>>(Wproj, WprojT, 768, 768);
  k_gemm_qkv<<<dim3(18, 64), 256, 0, stream>>>(Xbf, WqkvT, bqkv, Q, K, V);
  k_transpose_v<<<dim3(2, 128, 24), dim3(32, 8), 0, stream>>>(V, Vt);
  k_attn<<<dim3(64, 24), 256, 0, stream>>>(Q, K, Vt, O);
  k_gemm_proj<<<dim3(6, 64), 256, 0, stream>>>(O, WprojT, bproj, out);
}

// Round 2
// 309.426 us; speedup vs baseline: 1.4223x; 1.4223x over previous
//
#include <hip/hip_runtime.h>

typedef unsigned short u16;
typedef unsigned int u32;
typedef __bf16 bf16x8 __attribute__((ext_vector_type(8)));
typedef float f32x4 __attribute__((ext_vector_type(4)));
typedef float f32x16 __attribute__((ext_vector_type(16)));
typedef u16 u16x4 __attribute__((ext_vector_type(4)));
typedef u32 u32x4 __attribute__((ext_vector_type(4)));

#define L2E 1.4426950408889634f

static __device__ __forceinline__ u16 f2bf(float f) {
  __bf16 h = (__bf16)f;
  return __builtin_bit_cast(u16, h);
}

static __device__ __forceinline__ u32 pk2(float a, float b) {
  return (u32)f2bf(a) | ((u32)f2bf(b) << 16);
}

static __device__ __forceinline__ void gl_lds16(const void* g, void* l) {
  __builtin_amdgcn_global_load_lds(
      (const __attribute__((address_space(1))) unsigned int*)g,
      (__attribute__((address_space(3))) unsigned int*)l, 16, 0, 0);
}

static __device__ __forceinline__ f32x16 zero16() {
  f32x16 z;
#pragma unroll
  for (int i = 0; i < 16; ++i) z[i] = 0.f;
  return z;
}

// ---------------------------------------------------------------------------
// fp32 -> bf16 elementwise convert (vectorized x4)
// ---------------------------------------------------------------------------
__global__ void k_cvt(const float* __restrict__ in, u16* __restrict__ out, int n4) {
  int i = blockIdx.x * 256 + threadIdx.x;
  if (i < n4) {
    f32x4 f = ((const f32x4*)in)[i];
    u16x4 u = { f2bf(f[0]), f2bf(f[1]), f2bf(f[2]), f2bf(f[3]) };
    ((u16x4*)out)[i] = u;
  }
}

// ---------------------------------------------------------------------------
// fp32 [R][C] -> bf16 [C][R] transpose+convert. block (32,8), grid (C/32,R/32)
// ---------------------------------------------------------------------------
__global__ void k_transpose_cvt(const float* __restrict__ in, u16* __restrict__ out,
                                int R, int C) {
  __shared__ float tile[32][33];
  const int c0 = blockIdx.x * 32, r0 = blockIdx.y * 32;
  const int tx = threadIdx.x, ty = threadIdx.y;
#pragma unroll
  for (int i = 0; i < 4; ++i)
    tile[ty + i * 8][tx] = in[(size_t)(r0 + ty + i * 8) * C + c0 + tx];
  __syncthreads();
#pragma unroll
  for (int i = 0; i < 4; ++i)
    out[(size_t)(c0 + ty + i * 8) * R + r0 + tx] = f2bf(tile[tx][ty + i * 8]);
}

// ---------------------------------------------------------------------------
// bf16 V [BH][4096][64] -> Vt [BH][64][4096]. block (32,8), grid (2,128,24)
// ---------------------------------------------------------------------------
__global__ void k_transpose_v(const u16* __restrict__ V, u16* __restrict__ Vt) {
  __shared__ u16 tile[32][33];
  const int bh = blockIdx.z;
  const int d0 = blockIdx.x * 32, t0 = blockIdx.y * 32;
  const int tx = threadIdx.x, ty = threadIdx.y;
#pragma unroll
  for (int i = 0; i < 4; ++i)
    tile[ty + i * 8][tx] = V[((size_t)bh * 4096 + t0 + ty + i * 8) * 64 + d0 + tx];
  __syncthreads();
#pragma unroll
  for (int i = 0; i < 4; ++i)
    Vt[((size_t)bh * 64 + d0 + ty + i * 8) * 4096 + t0 + tx] = tile[tx][ty + i * 8];
}

// ---------------------------------------------------------------------------
// Shared GEMM mainloop: C[128x128] = A[M][K] * Bt[N][K]^T, bf16, BK=64.
// ---------------------------------------------------------------------------
static __device__ __forceinline__ void gemm_core(const u16* __restrict__ Ag,
                                                 const u16* __restrict__ Btg,
                                                 int K, int m0, int n0,
                                                 u16* As, u16* Bs,
                                                 f32x4 acc[4][4]) {
  const int tid = threadIdx.x;
  const int lane = tid & 63;
  const int wid = tid >> 6;
  const int wm = wid >> 1, wn = wid & 1;
  const int l16 = lane & 15, lg = lane >> 4;

  for (int kt = 0; kt < K; kt += 64) {
    __syncthreads();
#pragma unroll
    for (int i = 0; i < 4; ++i) {
      int chunk = i * 256 + tid;
      int row = chunk >> 3;
      int lcb = ((chunk & 7) << 4) ^ ((row & 7) << 4);
      gl_lds16(Ag + (size_t)(m0 + row) * K + kt + (lcb >> 1),
               As + ((i * 256 + wid * 64) << 3));
    }
#pragma unroll
    for (int i = 0; i < 4; ++i) {
      int chunk = i * 256 + tid;
      int row = chunk >> 3;
      int lcb = ((chunk & 7) << 4) ^ ((row & 7) << 4);
      gl_lds16(Btg + (size_t)(n0 + row) * K + kt + (lcb >> 1),
               Bs + ((i * 256 + wid * 64) << 3));
    }
    __syncthreads();

#pragma unroll
    for (int ks = 0; ks < 2; ++ks) {
      bf16x8 af[4], bfr[4];
#pragma unroll
      for (int mi = 0; mi < 4; ++mi) {
        int row = wm * 64 + mi * 16 + l16;
        int off = row * 128 + ((ks * 64 + (lg << 4)) ^ ((row & 7) << 4));
        af[mi] = *(const bf16x8*)((const char*)As + off);
      }
#pragma unroll
      for (int ni = 0; ni < 4; ++ni) {
        int row = wn * 64 + ni * 16 + l16;
        int off = row * 128 + ((ks * 64 + (lg << 4)) ^ ((row & 7) << 4));
        bfr[ni] = *(const bf16x8*)((const char*)Bs + off);
      }
#pragma unroll
      for (int mi = 0; mi < 4; ++mi)
#pragma unroll
        for (int ni = 0; ni < 4; ++ni)
          acc[mi][ni] = __builtin_amdgcn_mfma_f32_16x16x32_bf16(
              af[mi], bfr[ni], acc[mi][ni], 0, 0, 0);
    }
  }
}

// ---------------------------------------------------------------------------
// GEMM1: Xbf[8192][768] * WqkvT[2304][768]^T + bqkv -> scatter Q,K,V [BH][T][64]
// ---------------------------------------------------------------------------
__global__ __launch_bounds__(256) void k_gemm_qkv(
    const u16* __restrict__ A, const u16* __restrict__ Bt,
    const float* __restrict__ bias, u16* __restrict__ Q, u16* __restrict__ Kb,
    u16* __restrict__ V) {
  __shared__ __align__(16) u16 As[128 * 64];
  __shared__ __align__(16) u16 Bs[128 * 64];
  const int m0 = blockIdx.y * 128, n0 = blockIdx.x * 128;
  const f32x4 fz = {0.f, 0.f, 0.f, 0.f};
  f32x4 acc[4][4];
#pragma unroll
  for (int mi = 0; mi < 4; ++mi)
#pragma unroll
    for (int ni = 0; ni < 4; ++ni) acc[mi][ni] = fz;

  gemm_core(A, Bt, 768, m0, n0, As, Bs, acc);

  const int tid = threadIdx.x, lane = tid & 63, wid = tid >> 6;
  const int wm = wid >> 1, wn = wid & 1, l16 = lane & 15, lg = lane >> 4;
#pragma unroll
  for (int mi = 0; mi < 4; ++mi)
#pragma unroll
    for (int ni = 0; ni < 4; ++ni) {
      int n = n0 + wn * 64 + ni * 16 + l16;
      float bi = bias[n];
      int h = n / 192;
      int rr = n - h * 192;
#pragma unroll
      for (int r = 0; r < 4; ++r) {
        int m = m0 + wm * 64 + mi * 16 + lg * 4 + r;
        int b = m >> 12, t = m & 4095;
        float v = acc[mi][ni][r] + bi;
        size_t base = ((size_t)(b * 12 + h) * 4096 + t) * 64;
        u16 bv = f2bf(v);
        if (rr < 64)
          Q[base + rr] = bv;
        else if (rr < 128)
          Kb[base + rr - 64] = bv;
        else
          V[base + rr - 128] = bv;
      }
    }
}

// ---------------------------------------------------------------------------
// GEMM2: O[8192][768] * WprojT[768][768]^T + bproj -> out fp32
// ---------------------------------------------------------------------------
__global__ __launch_bounds__(256) void k_gemm_proj(
    const u16* __restrict__ A, const u16* __restrict__ Bt,
    const float* __restrict__ bias, float* __restrict__ out) {
  __shared__ __align__(16) u16 As[128 * 64];
  __shared__ __align__(16) u16 Bs[128 * 64];
  const int m0 = blockIdx.y * 128, n0 = blockIdx.x * 128;
  const f32x4 fz = {0.f, 0.f, 0.f, 0.f};
  f32x4 acc[4][4];
#pragma unroll
  for (int mi = 0; mi < 4; ++mi)
#pragma unroll
    for (int ni = 0; ni < 4; ++ni) acc[mi][ni] = fz;

  gemm_core(A, Bt, 768, m0, n0, As, Bs, acc);

  const int tid = threadIdx.x, lane = tid & 63, wid = tid >> 6;
  const int wm = wid >> 1, wn = wid & 1, l16 = lane & 15, lg = lane >> 4;
#pragma unroll
  for (int mi = 0; mi < 4; ++mi)
#pragma unroll
    for (int ni = 0; ni < 4; ++ni) {
      int n = n0 + wn * 64 + ni * 16 + l16;
      float bi = bias[n];
#pragma unroll
      for (int r = 0; r < 4; ++r) {
        int m = m0 + wm * 64 + mi * 16 + lg * 4 + r;
        out[(size_t)m * 768 + n] = acc[mi][ni][r] + bi;
      }
    }
}

// ---------------------------------------------------------------------------
// Flash attention, causal, swapped-operand 32x32 MFMA (m214 structure).
// grid (32, 24), 256 threads = 4 waves. Block: 128 q-rows (wave w: 32 rows).
// KV tiles of 64 staged in swizzled LDS (K [k][d], Vt [d][k]).
// S^T = mfma(A=K, B=Q): lane l32 = q-column; softmax lane-local + 1 shfl.
// O^T = mfma(A=Vt, B=P^T): alpha rescale is per-lane vector op.
// ---------------------------------------------------------------------------
__global__ __launch_bounds__(256) void k_attn(const u16* __restrict__ Qg,
                                              const u16* __restrict__ Kg,
                                              const u16* __restrict__ Vtg,
                                              u16* __restrict__ Og) {
  __shared__ __align__(16) u16 Ks[64 * 64];
  __shared__ __align__(16) u16 Vs[64 * 64];  // [d][kpos]
  const int qt = (int)gridDim.x - 1 - (int)blockIdx.x;  // heavy blocks first
  const int bh = blockIdx.y;
  const int tid = threadIdx.x;
  const int lane = tid & 63;
  const int wid = tid >> 6;
  const int l32 = lane & 31;
  const int hi = lane >> 5;
  const size_t qk_base = (size_t)bh * (4096 * 64);
  const int q0w = qt * 128 + wid * 32;
  const int qrow = q0w + l32;   // this lane's q row
  const int lastkt = (q0w + 31) >> 6;

  // Q as MFMA B-operand fragments: col=q(=l32), k=(hi)*8+j+16*st
  bf16x8 qb[4];
#pragma unroll
  for (int st = 0; st < 4; ++st)
    qb[st] = *(const bf16x8*)(Qg + qk_base + (size_t)qrow * 64 + st * 16 + hi * 8);

  f32x16 o0 = zero16(), o1 = zero16();  // O^T: row=d via reg, col=q=l32
  float mrun = -3.0e38f, lrun = 0.f;
  const float C2 = 0.125f * L2E;  // fold 1/sqrt(64) and log2(e)

  const int nkt = 2 * qt + 2;
  for (int kt = 0; kt < nkt; ++kt) {
    __syncthreads();
    // stage K tile [64 kpos][64 d] and Vt tile [64 d][64 kpos], pre-swizzled src
#pragma unroll
    for (int i = 0; i < 2; ++i) {
      int chunk = i * 256 + tid;
      int row = chunk >> 3;
      int lcb = ((chunk & 7) << 4) ^ ((row & 7) << 4);
      gl_lds16(Kg + qk_base + (size_t)(kt * 64 + row) * 64 + (lcb >> 1),
               Ks + ((i * 256 + wid * 64) << 3));
    }
#pragma unroll
    for (int i = 0; i < 2; ++i) {
      int chunk = i * 256 + tid;
      int row = chunk >> 3;
      int lcb = ((chunk & 7) << 4) ^ ((row & 7) << 4);
      gl_lds16(Vtg + (size_t)(bh * 64 + row) * 4096 + kt * 64 + (lcb >> 1),
               Vs + ((i * 256 + wid * 64) << 3));
    }
    __syncthreads();

    if (kt <= lastkt) {  // wave-uniform: skip fully-masked tiles
      // ---- S^T = K . Q^T : D row = kpos_local, col = q ----
      f32x16 s0 = zero16(), s1 = zero16();
#pragma unroll
      for (int st = 0; st < 4; ++st) {
        int r0 = l32;
        int off0 = r0 * 128 + ((st * 32 + hi * 16) ^ ((r0 & 7) << 4));
        bf16x8 ka0 = *(const bf16x8*)((const char*)Ks + off0);
        s0 = __builtin_amdgcn_mfma_f32_32x32x16_bf16(ka0, qb[st], s0, 0, 0, 0);
        int r1 = 32 + l32;
        int off1 = r1 * 128 + ((st * 32 + hi * 16) ^ ((r1 & 7) << 4));
        bf16x8 ka1 = *(const bf16x8*)((const char*)Ks + off1);
        s1 = __builtin_amdgcn_mfma_f32_32x32x16_bf16(ka1, qb[st], s1, 0, 0, 0);
      }

      // ---- scale + causal mask into exp2-domain ----
      f32x16 p0, p1;
      const int kbase = kt * 64 + 4 * hi;
#pragma unroll
      for (int r = 0; r < 16; ++r) {
        int kp = kbase + (r & 3) + 8 * (r >> 2);
        p0[r] = (kp > qrow) ? -3.0e38f : s0[r] * C2;
        p1[r] = (kp + 32 > qrow) ? -3.0e38f : s1[r] * C2;
      }

      // ---- online softmax: lane-local trees + one cross-half shfl ----
      float t[16];
#pragma unroll
      for (int r = 0; r < 16; ++r) t[r] = fmaxf(p0[r], p1[r]);
#pragma unroll
      for (int stp = 8; stp >= 1; stp >>= 1)
#pragma unroll
        for (int r = 0; r < 8; ++r)
          if (r < stp) t[r] = fmaxf(t[r], t[r + stp]);
      float mx = fmaxf(t[0], __shfl_xor(t[0], 32, 64));
      float mnew = fmaxf(mrun, mx);
      float alpha = __builtin_amdgcn_exp2f(mrun - mnew);
#pragma unroll
      for (int r = 0; r < 16; ++r) {
        p0[r] = __builtin_amdgcn_exp2f(p0[r] - mnew);
        p1[r] = __builtin_amdgcn_exp2f(p1[r] - mnew);
      }
#pragma unroll
      for (int r = 0; r < 16; ++r) t[r] = p0[r] + p1[r];
#pragma unroll
      for (int stp = 8; stp >= 1; stp >>= 1)
#pragma unroll
        for (int r = 0; r < 8; ++r)
          if (r < stp) t[r] += t[r + stp];
      float rs = t[0] + __shfl_xor(t[0], 32, 64);
      lrun = lrun * alpha + rs;
      mrun = mnew;
      o0 *= alpha;
      o1 *= alpha;

      // ---- P -> bf16 B-fragments (in-register exchange across hi halves) ----
      bf16x8 pb[4];
#pragma unroll
      for (int ks = 0; ks < 4; ++ks) {
        const f32x16& P = (ks >= 2) ? p1 : p0;
        const int base = 8 * (ks & 1);
        float own0 = hi ? P[base + 4] : P[base + 0];
        float own1 = hi ? P[base + 5] : P[base + 1];
        float own2 = hi ? P[base + 6] : P[base + 2];
        float own3 = hi ? P[base + 7] : P[base + 3];
        float snd0 = hi ? P[base + 0] : P[base + 4];
        float snd1 = hi ? P[base + 1] : P[base + 5];
        float snd2 = hi ? P[base + 2] : P[base + 6];
        float snd3 = hi ? P[base + 3] : P[base + 7];
        u32 ow0 = pk2(own0, own1), ow1 = pk2(own2, own3);
        u32 sd0 = pk2(snd0, snd1), sd1 = pk2(snd2, snd3);
        u32 rc0 = (u32)__shfl_xor((int)sd0, 32, 64);
        u32 rc1 = (u32)__shfl_xor((int)sd1, 32, 64);
        u32x4 w = { hi ? rc0 : ow0, hi ? rc1 : ow1,
                    hi ? ow0 : rc0, hi ? ow1 : rc1 };
        pb[ks] = __builtin_bit_cast(bf16x8, w);
      }

      // ---- O^T += Vt . P^T ----
#pragma unroll
      for (int ks = 0; ks < 4; ++ks) {
        int r0 = l32;
        int off0 = r0 * 128 + ((ks * 32 + hi * 16) ^ ((r0 & 7) << 4));
        bf16x8 va0 = *(const bf16x8*)((const char*)Vs + off0);
        o0 = __builtin_amdgcn_mfma_f32_32x32x16_bf16(va0, pb[ks], o0, 0, 0, 0);
        int r1 = 32 + l32;
        int off1 = r1 * 128 + ((ks * 32 + hi * 16) ^ ((r1 & 7) << 4));
        bf16x8 va1 = *(const bf16x8*)((const char*)Vs + off1);
        o1 = __builtin_amdgcn_mfma_f32_32x32x16_bf16(va1, pb[ks], o1, 0, 0, 0);
      }
    }
  }

  // ---- finalize: O^T reg r -> d = (r&3)+8*(r>>2)+4*hi (+32 for o1) ----
  float inv = 1.0f / lrun;
  const int b = bh / 12, h = bh - b * 12;
  u16* orow = Og + ((size_t)b * 4096 + qrow) * 768 + h * 64;
#pragma unroll
  for (int g = 0; g < 4; ++g) {
    u16x4 v0, v1;
#pragma unroll
    for (int i = 0; i < 4; ++i) {
      v0[i] = f2bf(o0[4 * g + i] * inv);
      v1[i] = f2bf(o1[4 * g + i] * inv);
    }
    *(u16x4*)(orow + 8 * g + 4 * hi) = v0;
    *(u16x4*)(orow + 32 + 8 * g + 4 * hi) = v1;
  }
}

// ---------------------------------------------------------------------------
// launch
// ---------------------------------------------------------------------------
extern "C" void kernel_launch(void* const* d_in, const int* in_sizes, int n_in,
                              void* d_out, int out_size, void* d_ws, size_t ws_size,
                              hipStream_t stream) {
  const float* x = (const float*)d_in[0];
  const float* Wqkv = (const float*)d_in[1];
  const float* bqkv = (const float*)d_in[2];
  const float* Wproj = (const float*)d_in[3];
  const float* bproj = (const float*)d_in[4];
  float* out = (float*)d_out;

  char* ws = (char*)d_ws;
  u16* Xbf = (u16*)(ws + 0);            // 12,582,912
  u16* WqkvT = (u16*)(ws + 12582912);   //  3,538,944
  u16* WprojT = (u16*)(ws + 16121856);  //  1,179,648
  u16* Q = (u16*)(ws + 17301504);       // 12,582,912
  u16* K = (u16*)(ws + 29884416);       // 12,582,912
  u16* V = (u16*)(ws + 42467328);       // 12,582,912
  u16* Vt = (u16*)(ws + 55050240);      // 12,582,912
  u16* O = (u16*)(ws + 67633152);       // 12,582,912

  k_cvt<<<6144, 256, 0, stream>>>(x, Xbf, 1572864);
  k_transpose_cvt<<<dim3(72, 24), dim3(32, 8), 0, stream>>>(Wqkv, WqkvT, 768, 2304);
  k_transpose_cvt<<<dim3(24, 24), dim3(32, 8), 0, stream>>>(Wproj, WprojT, 768, 768);
  k_gemm_qkv<<<dim3(18, 64), 256, 0, stream>>>(Xbf, WqkvT, bqkv, Q, K, V);
  k_transpose_v<<<dim3(2, 128, 24), dim3(32, 8), 0, stream>>>(V, Vt);
  k_attn<<<dim3(32, 24), 256, 0, stream>>>(Q, K, Vt, O);
  k_gemm_proj<<<dim3(6, 64), 256, 0, stream>>>(O, WprojT, bproj, out);
}

// Round 4
// 242.315 us; speedup vs baseline: 1.8162x; 1.2770x over previous
//
#include <hip/hip_runtime.h>

typedef unsigned short u16;
typedef unsigned int u32;
typedef __bf16 bf16x8 __attribute__((ext_vector_type(8)));
typedef float f32x4 __attribute__((ext_vector_type(4)));
typedef float f32x16 __attribute__((ext_vector_type(16)));
typedef u16 u16x4 __attribute__((ext_vector_type(4)));
typedef u32 u32x4 __attribute__((ext_vector_type(4)));

#define QSCALE 0.18033688011112042f  // 0.125 * log2(e), folded into Q

static __device__ __forceinline__ u16 f2bf(float f) {
  __bf16 h = (__bf16)f;
  return __builtin_bit_cast(u16, h);
}

static __device__ __forceinline__ u32 pk2(float a, float b) {
  return (u32)f2bf(a) | ((u32)f2bf(b) << 16);
}

static __device__ __forceinline__ void gl_lds16(const void* g, void* l) {
  __builtin_amdgcn_global_load_lds(
      (const __attribute__((address_space(1))) unsigned int*)g,
      (__attribute__((address_space(3))) unsigned int*)l, 16, 0, 0);
}

static __device__ __forceinline__ f32x16 zero16() {
  f32x16 z;
#pragma unroll
  for (int i = 0; i < 16; ++i) z[i] = 0.f;
  return z;
}

// ---------------------------------------------------------------------------
// fp32 -> bf16 elementwise convert (vectorized x4)
// ---------------------------------------------------------------------------
__global__ void k_cvt(const float* __restrict__ in, u16* __restrict__ out, int n4) {
  int i = blockIdx.x * 256 + threadIdx.x;
  if (i < n4) {
    f32x4 f = ((const f32x4*)in)[i];
    u16x4 u = { f2bf(f[0]), f2bf(f[1]), f2bf(f[2]), f2bf(f[3]) };
    ((u16x4*)out)[i] = u;
  }
}

// ---------------------------------------------------------------------------
// fp32 [R][C] -> bf16 [C][R] transpose+convert. block (32,8), grid (C/32,R/32)
// ---------------------------------------------------------------------------
__global__ void k_transpose_cvt(const float* __restrict__ in, u16* __restrict__ out,
                                int R, int C) {
  __shared__ float tile[32][33];
  const int c0 = blockIdx.x * 32, r0 = blockIdx.y * 32;
  const int tx = threadIdx.x, ty = threadIdx.y;
#pragma unroll
  for (int i = 0; i < 4; ++i)
    tile[ty + i * 8][tx] = in[(size_t)(r0 + ty + i * 8) * C + c0 + tx];
  __syncthreads();
#pragma unroll
  for (int i = 0; i < 4; ++i)
    out[(size_t)(c0 + ty + i * 8) * R + r0 + tx] = f2bf(tile[tx][ty + i * 8]);
}

// ---------------------------------------------------------------------------
// bf16 V [BH][4096][64] -> Vt [BH][64][4096]. block (32,8), grid (2,128,24)
// ---------------------------------------------------------------------------
__global__ void k_transpose_v(const u16* __restrict__ V, u16* __restrict__ Vt) {
  __shared__ u16 tile[32][33];
  const int bh = blockIdx.z;
  const int d0 = blockIdx.x * 32, t0 = blockIdx.y * 32;
  const int tx = threadIdx.x, ty = threadIdx.y;
#pragma unroll
  for (int i = 0; i < 4; ++i)
    tile[ty + i * 8][tx] = V[((size_t)bh * 4096 + t0 + ty + i * 8) * 64 + d0 + tx];
  __syncthreads();
#pragma unroll
  for (int i = 0; i < 4; ++i)
    Vt[((size_t)bh * 64 + d0 + ty + i * 8) * 4096 + t0 + tx] = tile[tx][ty + i * 8];
}

// ---------------------------------------------------------------------------
// Shared GEMM mainloop: C[128x128] = A[M][K] * Bt[N][K]^T, bf16, BK=64.
// ---------------------------------------------------------------------------
static __device__ __forceinline__ void gemm_core(const u16* __restrict__ Ag,
                                                 const u16* __restrict__ Btg,
                                                 int K, int m0, int n0,
                                                 u16* As, u16* Bs,
                                                 f32x4 acc[4][4]) {
  const int tid = threadIdx.x;
  const int lane = tid & 63;
  const int wid = tid >> 6;
  const int wm = wid >> 1, wn = wid & 1;
  const int l16 = lane & 15, lg = lane >> 4;

  for (int kt = 0; kt < K; kt += 64) {
    __syncthreads();
#pragma unroll
    for (int i = 0; i < 4; ++i) {
      int chunk = i * 256 + tid;
      int row = chunk >> 3;
      int lcb = ((chunk & 7) << 4) ^ ((row & 7) << 4);
      gl_lds16(Ag + (size_t)(m0 + row) * K + kt + (lcb >> 1),
               As + ((i * 256 + wid * 64) << 3));
    }
#pragma unroll
    for (int i = 0; i < 4; ++i) {
      int chunk = i * 256 + tid;
      int row = chunk >> 3;
      int lcb = ((chunk & 7) << 4) ^ ((row & 7) << 4);
      gl_lds16(Btg + (size_t)(n0 + row) * K + kt + (lcb >> 1),
               Bs + ((i * 256 + wid * 64) << 3));
    }
    __syncthreads();

#pragma unroll
    for (int ks = 0; ks < 2; ++ks) {
      bf16x8 af[4], bfr[4];
#pragma unroll
      for (int mi = 0; mi < 4; ++mi) {
        int row = wm * 64 + mi * 16 + l16;
        int off = row * 128 + ((ks * 64 + (lg << 4)) ^ ((row & 7) << 4));
        af[mi] = *(const bf16x8*)((const char*)As + off);
      }
#pragma unroll
      for (int ni = 0; ni < 4; ++ni) {
        int row = wn * 64 + ni * 16 + l16;
        int off = row * 128 + ((ks * 64 + (lg << 4)) ^ ((row & 7) << 4));
        bfr[ni] = *(const bf16x8*)((const char*)Bs + off);
      }
#pragma unroll
      for (int mi = 0; mi < 4; ++mi)
#pragma unroll
        for (int ni = 0; ni < 4; ++ni)
          acc[mi][ni] = __builtin_amdgcn_mfma_f32_16x16x32_bf16(
              af[mi], bfr[ni], acc[mi][ni], 0, 0, 0);
    }
  }
}

// ---------------------------------------------------------------------------
// GEMM1: Xbf[8192][768] * WqkvT[2304][768]^T + bqkv -> scatter Q,K,V [BH][T][64]
// Q is pre-scaled by 0.125*log2(e).
// ---------------------------------------------------------------------------
__global__ __launch_bounds__(256) void k_gemm_qkv(
    const u16* __restrict__ A, const u16* __restrict__ Bt,
    const float* __restrict__ bias, u16* __restrict__ Q, u16* __restrict__ Kb,
    u16* __restrict__ V) {
  __shared__ __align__(16) u16 As[128 * 64];
  __shared__ __align__(16) u16 Bs[128 * 64];
  const int m0 = blockIdx.y * 128, n0 = blockIdx.x * 128;
  const f32x4 fz = {0.f, 0.f, 0.f, 0.f};
  f32x4 acc[4][4];
#pragma unroll
  for (int mi = 0; mi < 4; ++mi)
#pragma unroll
    for (int ni = 0; ni < 4; ++ni) acc[mi][ni] = fz;

  gemm_core(A, Bt, 768, m0, n0, As, Bs, acc);

  const int tid = threadIdx.x, lane = tid & 63, wid = tid >> 6;
  const int wm = wid >> 1, wn = wid & 1, l16 = lane & 15, lg = lane >> 4;
#pragma unroll
  for (int mi = 0; mi < 4; ++mi)
#pragma unroll
    for (int ni = 0; ni < 4; ++ni) {
      int n = n0 + wn * 64 + ni * 16 + l16;
      float bi = bias[n];
      int h = n / 192;
      int rr = n - h * 192;
#pragma unroll
      for (int r = 0; r < 4; ++r) {
        int m = m0 + wm * 64 + mi * 16 + lg * 4 + r;
        int b = m >> 12, t = m & 4095;
        float v = acc[mi][ni][r] + bi;
        size_t base = ((size_t)(b * 12 + h) * 4096 + t) * 64;
        if (rr < 64)
          Q[base + rr] = f2bf(v * QSCALE);
        else if (rr < 128)
          Kb[base + rr - 64] = f2bf(v);
        else
          V[base + rr - 128] = f2bf(v);
      }
    }
}

// ---------------------------------------------------------------------------
// GEMM2: O[8192][768] * WprojT[768][768]^T + bproj -> out fp32
// ---------------------------------------------------------------------------
__global__ __launch_bounds__(256) void k_gemm_proj(
    const u16* __restrict__ A, const u16* __restrict__ Bt,
    const float* __restrict__ bias, float* __restrict__ out) {
  __shared__ __align__(16) u16 As[128 * 64];
  __shared__ __align__(16) u16 Bs[128 * 64];
  const int m0 = blockIdx.y * 128, n0 = blockIdx.x * 128;
  const f32x4 fz = {0.f, 0.f, 0.f, 0.f};
  f32x4 acc[4][4];
#pragma unroll
  for (int mi = 0; mi < 4; ++mi)
#pragma unroll
    for (int ni = 0; ni < 4; ++ni) acc[mi][ni] = fz;

  gemm_core(A, Bt, 768, m0, n0, As, Bs, acc);

  const int tid = threadIdx.x, lane = tid & 63, wid = tid >> 6;
  const int wm = wid >> 1, wn = wid & 1, l16 = lane & 15, lg = lane >> 4;
#pragma unroll
  for (int mi = 0; mi < 4; ++mi)
#pragma unroll
    for (int ni = 0; ni < 4; ++ni) {
      int n = n0 + wn * 64 + ni * 16 + l16;
      float bi = bias[n];
#pragma unroll
      for (int r = 0; r < 4; ++r) {
        int m = m0 + wm * 64 + mi * 16 + lg * 4 + r;
        out[(size_t)m * 768 + n] = acc[mi][ni][r] + bi;
      }
    }
}

// ---------------------------------------------------------------------------
// Flash attention, causal, swapped-operand 32x32 MFMA, double-buffered LDS,
// XCD-affine block mapping. grid 768 x 256 threads (4 waves x 32 q-rows).
// Cross-half exchange via __shfl_xor(32) (verified path; permlane asm NaN'd).
// ---------------------------------------------------------------------------
__global__ __launch_bounds__(256) void k_attn(const u16* __restrict__ Qg,
                                              const u16* __restrict__ Kg,
                                              const u16* __restrict__ Vtg,
                                              u16* __restrict__ Og) {
  __shared__ __align__(16) u16 Ks[2][64 * 64];
  __shared__ __align__(16) u16 Vs[2][64 * 64];  // [d][kpos]
  const int bid = blockIdx.x;
  const int sub = bid >> 3;
  const int bh = (bid & 7) * 3 + (sub >> 5);  // 8 XCDs x 3 heads
  const int qt = 31 - (sub & 31);             // heavy blocks first
  const int tid = threadIdx.x;
  const int lane = tid & 63;
  const int wid = tid >> 6;
  const int l32 = lane & 31;
  const int hi = lane >> 5;
  const size_t qk_base = (size_t)bh * (4096 * 64);
  const size_t vt_base = (size_t)bh * (64 * 4096);
  const int q0w = qt * 128 + wid * 32;
  const int qrow = q0w + l32;
  const int lastkt = (q0w + 31) >> 6;
  const int nkt = 2 * qt + 2;

  auto stage = [&](int buf, int kt) {
#pragma unroll
    for (int i = 0; i < 2; ++i) {
      int chunk = i * 256 + tid;
      int row = chunk >> 3;
      int lcb = ((chunk & 7) << 4) ^ ((row & 7) << 4);
      gl_lds16(Kg + qk_base + (size_t)(kt * 64 + row) * 64 + (lcb >> 1),
               Ks[buf] + ((i * 256 + wid * 64) << 3));
    }
#pragma unroll
    for (int i = 0; i < 2; ++i) {
      int chunk = i * 256 + tid;
      int row = chunk >> 3;
      int lcb = ((chunk & 7) << 4) ^ ((row & 7) << 4);
      gl_lds16(Vtg + vt_base + (size_t)row * 4096 + kt * 64 + (lcb >> 1),
               Vs[buf] + ((i * 256 + wid * 64) << 3));
    }
  };

  // Q fragments (B-operand): col=q(=l32), k=hi*8+j (+16*st). Pre-scaled.
  bf16x8 qb[4];
#pragma unroll
  for (int st = 0; st < 4; ++st)
    qb[st] = *(const bf16x8*)(Qg + qk_base + (size_t)qrow * 64 + st * 16 + hi * 8);

  f32x16 o0 = zero16(), o1 = zero16();  // O^T: d via (reg,hi), col q = l32
  float mrun = -3.0e38f, lrun = 0.f;

  stage(0, 0);
  __syncthreads();  // tile 0 ready

  int cur = 0;
  for (int kt = 0; kt < nkt; ++kt) {
    if (kt + 1 < nkt) stage(cur ^ 1, kt + 1);  // prefetch; drained at barrier

    if (kt <= lastkt) {
      const bool diag = (kt == lastkt);
      const bool halfskip = diag && ((q0w & 32) == 0);  // upper kp-half masked
      const u16* Kb = Ks[cur];
      const u16* Vb = Vs[cur];

      // ---- S^T = K . Q^T (log2-domain; scale folded into Q) ----
      f32x16 s0 = zero16(), s1 = zero16();
      __builtin_amdgcn_s_setprio(1);
#pragma unroll
      for (int st = 0; st < 4; ++st) {
        int r0 = l32;
        int off0 = r0 * 128 + ((st * 32 + hi * 16) ^ ((r0 & 7) << 4));
        bf16x8 ka0 = *(const bf16x8*)((const char*)Kb + off0);
        s0 = __builtin_amdgcn_mfma_f32_32x32x16_bf16(ka0, qb[st], s0, 0, 0, 0);
      }
      if (!halfskip) {
#pragma unroll
        for (int st = 0; st < 4; ++st) {
          int r1 = 32 + l32;
          int off1 = r1 * 128 + ((st * 32 + hi * 16) ^ ((r1 & 7) << 4));
          bf16x8 ka1 = *(const bf16x8*)((const char*)Kb + off1);
          s1 = __builtin_amdgcn_mfma_f32_32x32x16_bf16(ka1, qb[st], s1, 0, 0, 0);
        }
      }
      __builtin_amdgcn_s_setprio(0);

      // ---- causal mask: diagonal tile only ----
      if (diag) {
        const int kbase = kt * 64 + 4 * hi;
#pragma unroll
        for (int r = 0; r < 16; ++r) {
          int kp = kbase + (r & 3) + 8 * (r >> 2);
          s0[r] = (kp > qrow) ? -3.0e38f : s0[r];
          if (!halfskip) s1[r] = (kp + 32 > qrow) ? -3.0e38f : s1[r];
        }
      }

      // ---- row max (lane-local tree + cross-half shfl) ----
      float m8[8];
#pragma unroll
      for (int r = 0; r < 8; ++r) {
        float v = fmaxf(s0[r], s0[r + 8]);
        if (!halfskip) v = fmaxf(v, fmaxf(s1[r], s1[r + 8]));
        m8[r] = v;
      }
      float mx = fmaxf(fmaxf(fmaxf(m8[0], m8[1]), fmaxf(m8[2], m8[3])),
                       fmaxf(fmaxf(m8[4], m8[5]), fmaxf(m8[6], m8[7])));
      mx = fmaxf(mx, __shfl_xor(mx, 32, 64));

      // ---- defer-max rescale (T13, thr = 8 log2-units) ----
      if (__ballot(mx > mrun + 8.0f) != 0ull) {
        float mnew = fmaxf(mrun, mx);
        float al = __builtin_amdgcn_exp2f(mrun - mnew);
        o0 *= al;
        o1 *= al;
        lrun *= al;
        mrun = mnew;
      }

      // ---- exponentiate in place ----
#pragma unroll
      for (int r = 0; r < 16; ++r) {
        s0[r] = __builtin_amdgcn_exp2f(s0[r] - mrun);
        if (!halfskip) s1[r] = __builtin_amdgcn_exp2f(s1[r] - mrun);
      }

      // ---- row sum ----
      float a8[8];
#pragma unroll
      for (int r = 0; r < 8; ++r) {
        float v = s0[r] + s0[r + 8];
        if (!halfskip) v += s1[r] + s1[r + 8];
        a8[r] = v;
      }
      float rs = ((a8[0] + a8[1]) + (a8[2] + a8[3])) +
                 ((a8[4] + a8[5]) + (a8[6] + a8[7]));
      rs += __shfl_xor(rs, 32, 64);
      lrun += rs;

      // ---- P->bf16 fragments (shfl cross-half exchange) + PV ----
      __builtin_amdgcn_s_setprio(1);
#pragma unroll
      for (int ks = 0; ks < 4; ++ks) {
        if (ks >= 2 && halfskip) continue;
        const f32x16& P = (ks >= 2) ? s1 : s0;
        const int base = (ks & 1) * 8;
        float own0 = hi ? P[base + 4] : P[base + 0];
        float own1 = hi ? P[base + 5] : P[base + 1];
        float own2 = hi ? P[base + 6] : P[base + 2];
        float own3 = hi ? P[base + 7] : P[base + 3];
        float snd0 = hi ? P[base + 0] : P[base + 4];
        float snd1 = hi ? P[base + 1] : P[base + 5];
        float snd2 = hi ? P[base + 2] : P[base + 6];
        float snd3 = hi ? P[base + 3] : P[base + 7];
        u32 ow0 = pk2(own0, own1), ow1 = pk2(own2, own3);
        u32 sd0 = pk2(snd0, snd1), sd1 = pk2(snd2, snd3);
        u32 rc0 = (u32)__shfl_xor((int)sd0, 32, 64);
        u32 rc1 = (u32)__shfl_xor((int)sd1, 32, 64);
        u32x4 w = { hi ? rc0 : ow0, hi ? rc1 : ow1,
                    hi ? ow0 : rc0, hi ? ow1 : rc1 };
        bf16x8 pbk = __builtin_bit_cast(bf16x8, w);
        int r0 = l32;
        int off0 = r0 * 128 + ((ks * 32 + hi * 16) ^ ((r0 & 7) << 4));
        bf16x8 va0 = *(const bf16x8*)((const char*)Vb + off0);
        o0 = __builtin_amdgcn_mfma_f32_32x32x16_bf16(va0, pbk, o0, 0, 0, 0);
        int r1 = 32 + l32;
        int off1 = r1 * 128 + ((ks * 32 + hi * 16) ^ ((r1 & 7) << 4));
        bf16x8 va1 = *(const bf16x8*)((const char*)Vb + off1);
        o1 = __builtin_amdgcn_mfma_f32_32x32x16_bf16(va1, pbk, o1, 0, 0, 0);
      }
      __builtin_amdgcn_s_setprio(0);
    }

    __syncthreads();  // prefetch landed; next tile ready
    cur ^= 1;
  }

  // ---- finalize: O^T reg r -> d = (r&3)+8*(r>>2)+4*hi (+32 for o1) ----
  float inv = 1.0f / lrun;
  const int b = bh / 12, h = bh - b * 12;
  u16* orow = Og + ((size_t)b * 4096 + qrow) * 768 + h * 64;
#pragma unroll
  for (int g = 0; g < 4; ++g) {
    u16x4 v0, v1;
#pragma unroll
    for (int i = 0; i < 4; ++i) {
      v0[i] = f2bf(o0[4 * g + i] * inv);
      v1[i] = f2bf(o1[4 * g + i] * inv);
    }
    *(u16x4*)(orow + 8 * g + 4 * hi) = v0;
    *(u16x4*)(orow + 32 + 8 * g + 4 * hi) = v1;
  }
}

// ---------------------------------------------------------------------------
// launch
// ---------------------------------------------------------------------------
extern "C" void kernel_launch(void* const* d_in, const int* in_sizes, int n_in,
                              void* d_out, int out_size, void* d_ws, size_t ws_size,
                              hipStream_t stream) {
  const float* x = (const float*)d_in[0];
  const float* Wqkv = (const float*)d_in[1];
  const float* bqkv = (const float*)d_in[2];
  const float* Wproj = (const float*)d_in[3];
  const float* bproj = (const float*)d_in[4];
  float* out = (float*)d_out;

  char* ws = (char*)d_ws;
  u16* Xbf = (u16*)(ws + 0);            // 12,582,912
  u16* WqkvT = (u16*)(ws + 12582912);   //  3,538,944
  u16* WprojT = (u16*)(ws + 16121856);  //  1,179,648
  u16* Q = (u16*)(ws + 17301504);       // 12,582,912
  u16* K = (u16*)(ws + 29884416);       // 12,582,912
  u16* V = (u16*)(ws + 42467328);       // 12,582,912
  u16* Vt = (u16*)(ws + 55050240);      // 12,582,912
  u16* O = (u16*)(ws + 67633152);       // 12,582,912

  k_cvt<<<6144, 256, 0, stream>>>(x, Xbf, 1572864);
  k_transpose_cvt<<<dim3(72, 24), dim3(32, 8), 0, stream>>>(Wqkv, WqkvT, 768, 2304);
  k_transpose_cvt<<<dim3(24, 24), dim3(32, 8), 0, stream>>>(Wproj, WprojT, 768, 768);
  k_gemm_qkv<<<dim3(18, 64), 256, 0, stream>>>(Xbf, WqkvT, bqkv, Q, K, V);
  k_transpose_v<<<dim3(2, 128, 24), dim3(32, 8), 0, stream>>>(V, Vt);
  k_attn<<<768, 256, 0, stream>>>(Q, K, Vt, O);
  k_gemm_proj<<<dim3(6, 64), 256, 0, stream>>>(O, WprojT, bproj, out);
}

// Round 5
// 219.864 us; speedup vs baseline: 2.0017x; 1.1021x over previous
//
#include <hip/hip_runtime.h>

typedef unsigned short u16;
typedef unsigned int u32;
typedef __bf16 bf16x8 __attribute__((ext_vector_type(8)));
typedef float f32x4 __attribute__((ext_vector_type(4)));
typedef float f32x16 __attribute__((ext_vector_type(16)));
typedef u16 u16x4 __attribute__((ext_vector_type(4)));
typedef u32 u32x2 __attribute__((ext_vector_type(2)));
typedef u32 u32x4 __attribute__((ext_vector_type(4)));

#define QSCALE 0.18033688011112042f  // 0.125 * log2(e), folded into Q

static __device__ __forceinline__ u16 f2bf(float f) {
  __bf16 h = (__bf16)f;
  return __builtin_bit_cast(u16, h);
}

static __device__ __forceinline__ u32 pk2(float a, float b) {
  return (u32)f2bf(a) | ((u32)f2bf(b) << 16);
}

static __device__ __forceinline__ void gl_lds16(const void* g, void* l) {
  __builtin_amdgcn_global_load_lds(
      (const __attribute__((address_space(1))) unsigned int*)g,
      (__attribute__((address_space(3))) unsigned int*)l, 16, 0, 0);
}

static __device__ __forceinline__ f32x16 zero16() {
  f32x16 z;
#pragma unroll
  for (int i = 0; i < 16; ++i) z[i] = 0.f;
  return z;
}

// ---------------------------------------------------------------------------
// fp32 -> bf16 elementwise convert (vectorized x4)
// ---------------------------------------------------------------------------
__global__ void k_cvt(const float* __restrict__ in, u16* __restrict__ out, int n4) {
  int i = blockIdx.x * 256 + threadIdx.x;
  if (i < n4) {
    f32x4 f = ((const f32x4*)in)[i];
    u16x4 u = { f2bf(f[0]), f2bf(f[1]), f2bf(f[2]), f2bf(f[3]) };
    ((u16x4*)out)[i] = u;
  }
}

// ---------------------------------------------------------------------------
// fp32 [R][C] -> bf16 [C][R] transpose+convert. block (32,8), grid (C/32,R/32)
// ---------------------------------------------------------------------------
__global__ void k_transpose_cvt(const float* __restrict__ in, u16* __restrict__ out,
                                int R, int C) {
  __shared__ float tile[32][33];
  const int c0 = blockIdx.x * 32, r0 = blockIdx.y * 32;
  const int tx = threadIdx.x, ty = threadIdx.y;
#pragma unroll
  for (int i = 0; i < 4; ++i)
    tile[ty + i * 8][tx] = in[(size_t)(r0 + ty + i * 8) * C + c0 + tx];
  __syncthreads();
#pragma unroll
  for (int i = 0; i < 4; ++i)
    out[(size_t)(c0 + ty + i * 8) * R + r0 + tx] = f2bf(tile[tx][ty + i * 8]);
}

// ---------------------------------------------------------------------------
// Shared GEMM mainloop: C[128x128] = A[M][K] * Bt[N][K]^T, bf16, BK=64.
// ---------------------------------------------------------------------------
static __device__ __forceinline__ void gemm_core(const u16* __restrict__ Ag,
                                                 const u16* __restrict__ Btg,
                                                 int K, int m0, int n0,
                                                 u16* As, u16* Bs,
                                                 f32x4 acc[4][4]) {
  const int tid = threadIdx.x;
  const int lane = tid & 63;
  const int wid = tid >> 6;
  const int wm = wid >> 1, wn = wid & 1;
  const int l16 = lane & 15, lg = lane >> 4;

  for (int kt = 0; kt < K; kt += 64) {
    __syncthreads();
#pragma unroll
    for (int i = 0; i < 4; ++i) {
      int chunk = i * 256 + tid;
      int row = chunk >> 3;
      int lcb = ((chunk & 7) << 4) ^ ((row & 7) << 4);
      gl_lds16(Ag + (size_t)(m0 + row) * K + kt + (lcb >> 1),
               As + ((i * 256 + wid * 64) << 3));
    }
#pragma unroll
    for (int i = 0; i < 4; ++i) {
      int chunk = i * 256 + tid;
      int row = chunk >> 3;
      int lcb = ((chunk & 7) << 4) ^ ((row & 7) << 4);
      gl_lds16(Btg + (size_t)(n0 + row) * K + kt + (lcb >> 1),
               Bs + ((i * 256 + wid * 64) << 3));
    }
    __syncthreads();

#pragma unroll
    for (int ks = 0; ks < 2; ++ks) {
      bf16x8 af[4], bfr[4];
#pragma unroll
      for (int mi = 0; mi < 4; ++mi) {
        int row = wm * 64 + mi * 16 + l16;
        int off = row * 128 + ((ks * 64 + (lg << 4)) ^ ((row & 7) << 4));
        af[mi] = *(const bf16x8*)((const char*)As + off);
      }
#pragma unroll
      for (int ni = 0; ni < 4; ++ni) {
        int row = wn * 64 + ni * 16 + l16;
        int off = row * 128 + ((ks * 64 + (lg << 4)) ^ ((row & 7) << 4));
        bfr[ni] = *(const bf16x8*)((const char*)Bs + off);
      }
#pragma unroll
      for (int mi = 0; mi < 4; ++mi)
#pragma unroll
        for (int ni = 0; ni < 4; ++ni)
          acc[mi][ni] = __builtin_amdgcn_mfma_f32_16x16x32_bf16(
              af[mi], bfr[ni], acc[mi][ni], 0, 0, 0);
    }
  }
}

// ---------------------------------------------------------------------------
// GEMM1: Xbf[8192][768] * WqkvT[2304][768]^T + bqkv -> Q,K [BH][T][64] and
// Vt [BH][64][T] (direct transposed write). Q pre-scaled by 0.125*log2(e).
// ---------------------------------------------------------------------------
__global__ __launch_bounds__(256) void k_gemm_qkv(
    const u16* __restrict__ A, const u16* __restrict__ Bt,
    const float* __restrict__ bias, u16* __restrict__ Q, u16* __restrict__ Kb,
    u16* __restrict__ Vt) {
  __shared__ __align__(16) u16 As[128 * 64];
  __shared__ __align__(16) u16 Bs[128 * 64];
  const int m0 = blockIdx.y * 128, n0 = blockIdx.x * 128;
  const f32x4 fz = {0.f, 0.f, 0.f, 0.f};
  f32x4 acc[4][4];
#pragma unroll
  for (int mi = 0; mi < 4; ++mi)
#pragma unroll
    for (int ni = 0; ni < 4; ++ni) acc[mi][ni] = fz;

  gemm_core(A, Bt, 768, m0, n0, As, Bs, acc);

  const int tid = threadIdx.x, lane = tid & 63, wid = tid >> 6;
  const int wm = wid >> 1, wn = wid & 1, l16 = lane & 15, lg = lane >> 4;
#pragma unroll
  for (int mi = 0; mi < 4; ++mi)
#pragma unroll
    for (int ni = 0; ni < 4; ++ni) {
      int n = n0 + wn * 64 + ni * 16 + l16;
      float bi = bias[n];
      int h = n / 192;
      int rr = n - h * 192;
      int m0w = m0 + wm * 64 + mi * 16 + lg * 4;
      int bb = m0w >> 12, t0 = m0w & 4095;
      size_t base = ((size_t)(bb * 12 + h) * 4096 + t0) * 64;
      if (rr < 64) {
#pragma unroll
        for (int r = 0; r < 4; ++r)
          Q[base + (size_t)r * 64 + rr] = f2bf((acc[mi][ni][r] + bi) * QSCALE);
      } else if (rr < 128) {
#pragma unroll
        for (int r = 0; r < 4; ++r)
          Kb[base + (size_t)r * 64 + rr - 64] = f2bf(acc[mi][ni][r] + bi);
      } else {
        u16x4 vv;
#pragma unroll
        for (int r = 0; r < 4; ++r) vv[r] = f2bf(acc[mi][ni][r] + bi);
        *(u16x4*)(Vt + ((size_t)(bb * 12 + h) * 64 + (rr - 128)) * 4096 + t0) = vv;
      }
    }
}

// ---------------------------------------------------------------------------
// GEMM2: O[8192][768] * WprojT[768][768]^T + bproj -> out fp32
// ---------------------------------------------------------------------------
__global__ __launch_bounds__(256) void k_gemm_proj(
    const u16* __restrict__ A, const u16* __restrict__ Bt,
    const float* __restrict__ bias, float* __restrict__ out) {
  __shared__ __align__(16) u16 As[128 * 64];
  __shared__ __align__(16) u16 Bs[128 * 64];
  const int m0 = blockIdx.y * 128, n0 = blockIdx.x * 128;
  const f32x4 fz = {0.f, 0.f, 0.f, 0.f};
  f32x4 acc[4][4];
#pragma unroll
  for (int mi = 0; mi < 4; ++mi)
#pragma unroll
    for (int ni = 0; ni < 4; ++ni) acc[mi][ni] = fz;

  gemm_core(A, Bt, 768, m0, n0, As, Bs, acc);

  const int tid = threadIdx.x, lane = tid & 63, wid = tid >> 6;
  const int wm = wid >> 1, wn = wid & 1, l16 = lane & 15, lg = lane >> 4;
#pragma unroll
  for (int mi = 0; mi < 4; ++mi)
#pragma unroll
    for (int ni = 0; ni < 4; ++ni) {
      int n = n0 + wn * 64 + ni * 16 + l16;
      float bi = bias[n];
#pragma unroll
      for (int r = 0; r < 4; ++r) {
        int m = m0 + wm * 64 + mi * 16 + lg * 4 + r;
        out[(size_t)m * 768 + n] = acc[mi][ni][r] + bi;
      }
    }
}

// ---------------------------------------------------------------------------
// Flash attention, causal, swapped-operand 32x32 MFMA.
// grid 768 x 128 threads (2 waves x 32 q-rows = 64-row q-tile).
// Each block processes paired q-tiles (j, 63-j): uniform 65 ktiles/block,
// exactly 3 blocks/CU, every wave active on every kt (perfect balance).
// PV uses k-permutation sigma so P fragments need NO cross-lane exchange:
// B reg j holds P[sigma(8hi+j)], A-side reads Vt at sigma-matched offsets
// (two ds_read_b64 per fragment). Same sigma both operands => exact result.
// ---------------------------------------------------------------------------
__global__ __launch_bounds__(128) void k_attn(const u16* __restrict__ Qg,
                                              const u16* __restrict__ Kg,
                                              const u16* __restrict__ Vtg,
                                              u16* __restrict__ Og) {
  __shared__ __align__(16) u16 Ks[2][64 * 64];
  __shared__ __align__(16) u16 Vs[2][64 * 64];  // [d][kpos]
  const int bid = blockIdx.x;
  const int sub = bid >> 3;
  const int bh = (bid & 7) * 3 + (sub >> 5);  // 8 XCDs x 3 heads
  const int jpair = sub & 31;
  const int tid = threadIdx.x;
  const int lane = tid & 63;
  const int wid = tid >> 6;  // 0..1
  const int l32 = lane & 31;
  const int hi = lane >> 5;
  const int rxor = (l32 & 7) << 4;
  const size_t qk_base = (size_t)bh * (4096 * 64);
  const size_t vt_base = (size_t)bh * (64 * 4096);
  const int b = bh / 12, h = bh - b * 12;

  // staging geometry (fixed per thread): 4 chunks each for K and V tiles
  int srow[4], scol[4], sdst[4];
#pragma unroll
  for (int i = 0; i < 4; ++i) {
    int chunk = i * 128 + tid;
    int row = chunk >> 3;
    int lcb = ((chunk & 7) << 4) ^ ((row & 7) << 4);
    srow[i] = row;
    scol[i] = lcb >> 1;   // u16 offset within row
    sdst[i] = chunk << 3; // u16 offset in LDS tile
  }

  auto process = [&](int jX) {
    const int q0w = jX * 64 + wid * 32;
    const int qrow = q0w + l32;
    const int nkt = jX + 1;

    // Q fragments (B-operand): col=q(=l32), k=hi*8+j (+16*st). Pre-scaled.
    bf16x8 qb[4];
#pragma unroll
    for (int st = 0; st < 4; ++st)
      qb[st] = *(const bf16x8*)(Qg + qk_base + (size_t)qrow * 64 + st * 16 + hi * 8);

    // staging pointers, bumped per ktile
    const u16* kp[4];
    const u16* vp[4];
#pragma unroll
    for (int i = 0; i < 4; ++i) {
      kp[i] = Kg + qk_base + (size_t)srow[i] * 64 + scol[i];
      vp[i] = Vtg + vt_base + (size_t)srow[i] * 4096 + scol[i];
    }

    f32x16 o0 = zero16(), o1 = zero16();
    float mrun = -3.0e38f, lrun = 0.f;

#pragma unroll
    for (int i = 0; i < 4; ++i) {  // stage tile 0 -> buf 0
      gl_lds16(kp[i], Ks[0] + sdst[i]);
      gl_lds16(vp[i], Vs[0] + sdst[i]);
      kp[i] += 4096;
      vp[i] += 64;
    }
    __syncthreads();

    int cur = 0;
    for (int kt = 0; kt < nkt; ++kt) {
      if (kt + 1 < nkt) {  // prefetch next tile; drained at end barrier
        int nb = cur ^ 1;
#pragma unroll
        for (int i = 0; i < 4; ++i) {
          gl_lds16(kp[i], Ks[nb] + sdst[i]);
          gl_lds16(vp[i], Vs[nb] + sdst[i]);
          kp[i] += 4096;
          vp[i] += 64;
        }
      }
      const bool diag = (kt == nkt - 1);
      const bool halfskip = diag && (wid == 0);  // upper 32 k fully masked
      const u16* Kb = Ks[cur];
      const u16* Vb = Vs[cur];

      // ---- S^T = K . Q^T (log2-domain) ----
      f32x16 s0 = zero16(), s1 = zero16();
      __builtin_amdgcn_s_setprio(1);
#pragma unroll
      for (int st = 0; st < 4; ++st) {
        int co = (st * 32 + hi * 16) ^ rxor;
        bf16x8 ka0 = *(const bf16x8*)((const char*)Kb + l32 * 128 + co);
        s0 = __builtin_amdgcn_mfma_f32_32x32x16_bf16(ka0, qb[st], s0, 0, 0, 0);
      }
      if (!halfskip) {
#pragma unroll
        for (int st = 0; st < 4; ++st) {
          int co = (st * 32 + hi * 16) ^ rxor;
          bf16x8 ka1 = *(const bf16x8*)((const char*)Kb + (32 + l32) * 128 + co);
          s1 = __builtin_amdgcn_mfma_f32_32x32x16_bf16(ka1, qb[st], s1, 0, 0, 0);
        }
      }
      __builtin_amdgcn_s_setprio(0);

      // ---- causal mask: diagonal tile only ----
      if (diag) {
        const int kbase = kt * 64 + 4 * hi;
#pragma unroll
        for (int r = 0; r < 16; ++r) {
          int kpv = kbase + (r & 3) + 8 * (r >> 2);
          s0[r] = (kpv > qrow) ? -3.0e38f : s0[r];
          if (!halfskip) s1[r] = (kpv + 32 > qrow) ? -3.0e38f : s1[r];
        }
      }

      // ---- row max (lane-local tree + cross-half shfl) ----
      float m8[8];
#pragma unroll
      for (int r = 0; r < 8; ++r) {
        float v = fmaxf(s0[r], s0[r + 8]);
        if (!halfskip) v = fmaxf(v, fmaxf(s1[r], s1[r + 8]));
        m8[r] = v;
      }
      float mx = fmaxf(fmaxf(fmaxf(m8[0], m8[1]), fmaxf(m8[2], m8[3])),
                       fmaxf(fmaxf(m8[4], m8[5]), fmaxf(m8[6], m8[7])));
      mx = fmaxf(mx, __shfl_xor(mx, 32, 64));

      // ---- defer-max rescale (thr = 8 log2-units) ----
      if (__ballot(mx > mrun + 8.0f) != 0ull) {
        float mnew = fmaxf(mrun, mx);
        float al = __builtin_amdgcn_exp2f(mrun - mnew);
        o0 *= al;
        o1 *= al;
        lrun *= al;
        mrun = mnew;
      }

      // ---- exponentiate in place ----
#pragma unroll
      for (int r = 0; r < 16; ++r) {
        s0[r] = __builtin_amdgcn_exp2f(s0[r] - mrun);
        if (!halfskip) s1[r] = __builtin_amdgcn_exp2f(s1[r] - mrun);
      }

      // ---- row sum ----
      float a8[8];
#pragma unroll
      for (int r = 0; r < 8; ++r) {
        float v = s0[r] + s0[r + 8];
        if (!halfskip) v += s1[r] + s1[r + 8];
        a8[r] = v;
      }
      float rs = ((a8[0] + a8[1]) + (a8[2] + a8[3])) +
                 ((a8[4] + a8[5]) + (a8[6] + a8[7]));
      rs += __shfl_xor(rs, 32, 64);
      lrun += rs;

      // ---- PV with k-permutation sigma (no cross-lane exchange) ----
      // B reg dwords: pk2 of P[base+0..7] pairs = P at k: 4hi+{0,1,2,3,8,9,10,11}
      // A reg: Vt[d][16ks + 4hi + {0..3}] and [16ks + 8 + 4hi + {0..3}]
      __builtin_amdgcn_s_setprio(1);
#pragma unroll
      for (int ks = 0; ks < 4; ++ks) {
        if (ks >= 2 && halfskip) continue;
        const f32x16& P = (ks >= 2) ? s1 : s0;
        const int base = (ks & 1) * 8;
        u32x4 w = { pk2(P[base + 0], P[base + 1]), pk2(P[base + 2], P[base + 3]),
                    pk2(P[base + 4], P[base + 5]), pk2(P[base + 6], P[base + 7]) };
        bf16x8 pbk = __builtin_bit_cast(bf16x8, w);
        int c0 = (ks * 32 + hi * 8) ^ rxor;
        int c1 = (ks * 32 + 16 + hi * 8) ^ rxor;
        u32x2 q0 = *(const u32x2*)((const char*)Vb + l32 * 128 + c0);
        u32x2 q1 = *(const u32x2*)((const char*)Vb + l32 * 128 + c1);
        u32x4 av = {q0[0], q0[1], q1[0], q1[1]};
        bf16x8 va0 = __builtin_bit_cast(bf16x8, av);
        o0 = __builtin_amdgcn_mfma_f32_32x32x16_bf16(va0, pbk, o0, 0, 0, 0);
        u32x2 p0 = *(const u32x2*)((const char*)Vb + (32 + l32) * 128 + c0);
        u32x2 p1 = *(const u32x2*)((const char*)Vb + (32 + l32) * 128 + c1);
        u32x4 bv = {p0[0], p0[1], p1[0], p1[1]};
        bf16x8 va1 = __builtin_bit_cast(bf16x8, bv);
        o1 = __builtin_amdgcn_mfma_f32_32x32x16_bf16(va1, pbk, o1, 0, 0, 0);
      }
      __builtin_amdgcn_s_setprio(0);

      __syncthreads();  // prefetch landed; LDS reads of cur complete
      cur ^= 1;
    }

    // ---- finalize: O^T reg r -> d = (r&3)+8*(r>>2)+4*hi (+32 for o1) ----
    float inv = 1.0f / lrun;
    u16* orow = Og + ((size_t)b * 4096 + qrow) * 768 + h * 64;
#pragma unroll
    for (int g = 0; g < 4; ++g) {
      u16x4 v0, v1;
#pragma unroll
      for (int i = 0; i < 4; ++i) {
        v0[i] = f2bf(o0[4 * g + i] * inv);
        v1[i] = f2bf(o1[4 * g + i] * inv);
      }
      *(u16x4*)(orow + 8 * g + 4 * hi) = v0;
      *(u16x4*)(orow + 32 + 8 * g + 4 * hi) = v1;
    }
  };

  process(jpair);
  process(63 - jpair);
}

// ---------------------------------------------------------------------------
// launch
// ---------------------------------------------------------------------------
extern "C" void kernel_launch(void* const* d_in, const int* in_sizes, int n_in,
                              void* d_out, int out_size, void* d_ws, size_t ws_size,
                              hipStream_t stream) {
  const float* x = (const float*)d_in[0];
  const float* Wqkv = (const float*)d_in[1];
  const float* bqkv = (const float*)d_in[2];
  const float* Wproj = (const float*)d_in[3];
  const float* bproj = (const float*)d_in[4];
  float* out = (float*)d_out;

  char* ws = (char*)d_ws;
  u16* Xbf = (u16*)(ws + 0);            // 12,582,912
  u16* WqkvT = (u16*)(ws + 12582912);   //  3,538,944
  u16* WprojT = (u16*)(ws + 16121856);  //  1,179,648
  u16* Q = (u16*)(ws + 17301504);       // 12,582,912
  u16* K = (u16*)(ws + 29884416);       // 12,582,912
  u16* Vt = (u16*)(ws + 42467328);      // 12,582,912
  u16* O = (u16*)(ws + 55050240);       // 12,582,912

  k_cvt<<<6144, 256, 0, stream>>>(x, Xbf, 1572864);
  k_transpose_cvt<<<dim3(72, 24), dim3(32, 8), 0, stream>>>(Wqkv, WqkvT, 768, 2304);
  k_transpose_cvt<<<dim3(24, 24), dim3(32, 8), 0, stream>>>(Wproj, WprojT, 768, 768);
  k_gemm_qkv<<<dim3(18, 64), 256, 0, stream>>>(Xbf, WqkvT, bqkv, Q, K, Vt);
  k_attn<<<768, 128, 0, stream>>>(Q, K, Vt, O);
  k_gemm_proj<<<dim3(6, 64), 256, 0, stream>>>(O, WprojT, bproj, out);
}

// Round 7
// 218.928 us; speedup vs baseline: 2.0103x; 1.0043x over previous
//
#include <hip/hip_runtime.h>

typedef unsigned short u16;
typedef unsigned int u32;
typedef __bf16 bf16x8 __attribute__((ext_vector_type(8)));
typedef float f32x4 __attribute__((ext_vector_type(4)));
typedef float f32x16 __attribute__((ext_vector_type(16)));
typedef u16 u16x4 __attribute__((ext_vector_type(4)));
typedef u32 u32x2 __attribute__((ext_vector_type(2)));
typedef u32 u32x4 __attribute__((ext_vector_type(4)));

#define QSCALE 0.18033688011112042f  // 0.125 * log2(e), folded into Q

static __device__ __forceinline__ u16 f2bf(float f) {
  __bf16 h = (__bf16)f;
  return __builtin_bit_cast(u16, h);
}

static __device__ __forceinline__ u32 pk2(float a, float b) {
  return (u32)f2bf(a) | ((u32)f2bf(b) << 16);
}

// NOTE: offset arg MUST stay 0 — non-zero immediate offset has unverified
// semantics on gfx950 (R6 failure: absmax 0.84 traced to gl_lds16o<2048>).
static __device__ __forceinline__ void gl_lds16(const void* g, void* l) {
  __builtin_amdgcn_global_load_lds(
      (const __attribute__((address_space(1))) unsigned int*)g,
      (__attribute__((address_space(3))) unsigned int*)l, 16, 0, 0);
}

static __device__ __forceinline__ f32x16 zero16() {
  f32x16 z;
#pragma unroll
  for (int i = 0; i < 16; ++i) z[i] = 0.f;
  return z;
}

// ---------------------------------------------------------------------------
// fp32 -> bf16 elementwise convert (vectorized x4)
// ---------------------------------------------------------------------------
__global__ void k_cvt(const float* __restrict__ in, u16* __restrict__ out, int n4) {
  int i = blockIdx.x * 256 + threadIdx.x;
  if (i < n4) {
    f32x4 f = ((const f32x4*)in)[i];
    u16x4 u = { f2bf(f[0]), f2bf(f[1]), f2bf(f[2]), f2bf(f[3]) };
    ((u16x4*)out)[i] = u;
  }
}

// ---------------------------------------------------------------------------
// fp32 [R][C] -> bf16 [C][R] transpose+convert. block (32,8), grid (C/32,R/32)
// ---------------------------------------------------------------------------
__global__ void k_transpose_cvt(const float* __restrict__ in, u16* __restrict__ out,
                                int R, int C) {
  __shared__ float tile[32][33];
  const int c0 = blockIdx.x * 32, r0 = blockIdx.y * 32;
  const int tx = threadIdx.x, ty = threadIdx.y;
#pragma unroll
  for (int i = 0; i < 4; ++i)
    tile[ty + i * 8][tx] = in[(size_t)(r0 + ty + i * 8) * C + c0 + tx];
  __syncthreads();
#pragma unroll
  for (int i = 0; i < 4; ++i)
    out[(size_t)(c0 + ty + i * 8) * R + r0 + tx] = f2bf(tile[tx][ty + i * 8]);
}

// ---------------------------------------------------------------------------
// Shared GEMM mainloop: C[128x128] = A[M][K] * Bt[N][K]^T, bf16, BK=64.
// ---------------------------------------------------------------------------
static __device__ __forceinline__ void gemm_core(const u16* __restrict__ Ag,
                                                 const u16* __restrict__ Btg,
                                                 int K, int m0, int n0,
                                                 u16* As, u16* Bs,
                                                 f32x4 acc[4][4]) {
  const int tid = threadIdx.x;
  const int lane = tid & 63;
  const int wid = tid >> 6;
  const int wm = wid >> 1, wn = wid & 1;
  const int l16 = lane & 15, lg = lane >> 4;

  for (int kt = 0; kt < K; kt += 64) {
    __syncthreads();
#pragma unroll
    for (int i = 0; i < 4; ++i) {
      int chunk = i * 256 + tid;
      int row = chunk >> 3;
      int lcb = ((chunk & 7) << 4) ^ ((row & 7) << 4);
      gl_lds16(Ag + (size_t)(m0 + row) * K + kt + (lcb >> 1),
               As + ((i * 256 + wid * 64) << 3));
    }
#pragma unroll
    for (int i = 0; i < 4; ++i) {
      int chunk = i * 256 + tid;
      int row = chunk >> 3;
      int lcb = ((chunk & 7) << 4) ^ ((row & 7) << 4);
      gl_lds16(Btg + (size_t)(n0 + row) * K + kt + (lcb >> 1),
               Bs + ((i * 256 + wid * 64) << 3));
    }
    __syncthreads();

#pragma unroll
    for (int ks = 0; ks < 2; ++ks) {
      bf16x8 af[4], bfr[4];
#pragma unroll
      for (int mi = 0; mi < 4; ++mi) {
        int row = wm * 64 + mi * 16 + l16;
        int off = row * 128 + ((ks * 64 + (lg << 4)) ^ ((row & 7) << 4));
        af[mi] = *(const bf16x8*)((const char*)As + off);
      }
#pragma unroll
      for (int ni = 0; ni < 4; ++ni) {
        int row = wn * 64 + ni * 16 + l16;
        int off = row * 128 + ((ks * 64 + (lg << 4)) ^ ((row & 7) << 4));
        bfr[ni] = *(const bf16x8*)((const char*)Bs + off);
      }
#pragma unroll
      for (int mi = 0; mi < 4; ++mi)
#pragma unroll
        for (int ni = 0; ni < 4; ++ni)
          acc[mi][ni] = __builtin_amdgcn_mfma_f32_16x16x32_bf16(
              af[mi], bfr[ni], acc[mi][ni], 0, 0, 0);
    }
  }
}

// ---------------------------------------------------------------------------
// GEMM1: Xbf[8192][768] * WqkvT[2304][768]^T + bqkv -> Q,K [BH][T][64] and
// Vt [BH][64][T] (direct transposed write). Q pre-scaled by 0.125*log2(e).
// ---------------------------------------------------------------------------
__global__ __launch_bounds__(256) void k_gemm_qkv(
    const u16* __restrict__ A, const u16* __restrict__ Bt,
    const float* __restrict__ bias, u16* __restrict__ Q, u16* __restrict__ Kb,
    u16* __restrict__ Vt) {
  __shared__ __align__(16) u16 As[128 * 64];
  __shared__ __align__(16) u16 Bs[128 * 64];
  const int m0 = blockIdx.y * 128, n0 = blockIdx.x * 128;
  const f32x4 fz = {0.f, 0.f, 0.f, 0.f};
  f32x4 acc[4][4];
#pragma unroll
  for (int mi = 0; mi < 4; ++mi)
#pragma unroll
    for (int ni = 0; ni < 4; ++ni) acc[mi][ni] = fz;

  gemm_core(A, Bt, 768, m0, n0, As, Bs, acc);

  const int tid = threadIdx.x, lane = tid & 63, wid = tid >> 6;
  const int wm = wid >> 1, wn = wid & 1, l16 = lane & 15, lg = lane >> 4;
#pragma unroll
  for (int mi = 0; mi < 4; ++mi)
#pragma unroll
    for (int ni = 0; ni < 4; ++ni) {
      int n = n0 + wn * 64 + ni * 16 + l16;
      float bi = bias[n];
      int h = n / 192;
      int rr = n - h * 192;
      int m0w = m0 + wm * 64 + mi * 16 + lg * 4;
      int bb = m0w >> 12, t0 = m0w & 4095;
      size_t base = ((size_t)(bb * 12 + h) * 4096 + t0) * 64;
      if (rr < 64) {
#pragma unroll
        for (int r = 0; r < 4; ++r)
          Q[base + (size_t)r * 64 + rr] = f2bf((acc[mi][ni][r] + bi) * QSCALE);
      } else if (rr < 128) {
#pragma unroll
        for (int r = 0; r < 4; ++r)
          Kb[base + (size_t)r * 64 + rr - 64] = f2bf(acc[mi][ni][r] + bi);
      } else {
        u16x4 vv;
#pragma unroll
        for (int r = 0; r < 4; ++r) vv[r] = f2bf(acc[mi][ni][r] + bi);
        *(u16x4*)(Vt + ((size_t)(bb * 12 + h) * 64 + (rr - 128)) * 4096 + t0) = vv;
      }
    }
}

// ---------------------------------------------------------------------------
// GEMM2: O[8192][768] * WprojT[768][768]^T + bproj -> out fp32
// ---------------------------------------------------------------------------
__global__ __launch_bounds__(256) void k_gemm_proj(
    const u16* __restrict__ A, const u16* __restrict__ Bt,
    const float* __restrict__ bias, float* __restrict__ out) {
  __shared__ __align__(16) u16 As[128 * 64];
  __shared__ __align__(16) u16 Bs[128 * 64];
  const int m0 = blockIdx.y * 128, n0 = blockIdx.x * 128;
  const f32x4 fz = {0.f, 0.f, 0.f, 0.f};
  f32x4 acc[4][4];
#pragma unroll
  for (int mi = 0; mi < 4; ++mi)
#pragma unroll
    for (int ni = 0; ni < 4; ++ni) acc[mi][ni] = fz;

  gemm_core(A, Bt, 768, m0, n0, As, Bs, acc);

  const int tid = threadIdx.x, lane = tid & 63, wid = tid >> 6;
  const int wm = wid >> 1, wn = wid & 1, l16 = lane & 15, lg = lane >> 4;
#pragma unroll
  for (int mi = 0; mi < 4; ++mi)
#pragma unroll
    for (int ni = 0; ni < 4; ++ni) {
      int n = n0 + wn * 64 + ni * 16 + l16;
      float bi = bias[n];
#pragma unroll
      for (int r = 0; r < 4; ++r) {
        int m = m0 + wm * 64 + mi * 16 + lg * 4 + r;
        out[(size_t)m * 768 + n] = acc[mi][ni][r] + bi;
      }
    }
}

// ---------------------------------------------------------------------------
// Flash attention, causal, swapped-operand 32x32 MFMA.
// grid 1536 x 128 threads: ONE 64-row q-tile per block (2 waves x 32 rows).
// 32KB LDS/block -> ~5 blocks/CU co-resident; causal imbalance absorbed by
// co-residency (heavy j first). XCD-affine: each bh's blocks on one XCD.
// Staging: R5-verified form — per-pointer addresses, offset always 0.
// ---------------------------------------------------------------------------
__global__ __launch_bounds__(128) void k_attn(const u16* __restrict__ Qg,
                                              const u16* __restrict__ Kg,
                                              const u16* __restrict__ Vtg,
                                              u16* __restrict__ Og) {
  __shared__ __align__(16) u16 Ks[2][64 * 64];
  __shared__ __align__(16) u16 Vs[2][64 * 64];  // [d][kpos]
  const int bid = blockIdx.x;
  const int xcd = bid & 7;
  const int g = bid >> 3;             // 0..191
  const int bh = xcd * 3 + (g >> 6);  // 3 heads per XCD
  const int jX = 63 - (g & 63);       // heavy q-tiles first
  const int tid = threadIdx.x;
  const int lane = tid & 63;
  const int wid = tid >> 6;  // 0..1
  const int l32 = lane & 31;
  const int hi = lane >> 5;
  const int rxor = (l32 & 7) << 4;
  const size_t qk_base = (size_t)bh * (4096 * 64);
  const size_t vt_base = (size_t)bh * (64 * 4096);
  const int b = bh / 12, h = bh - b * 12;

  const int q0w = jX * 64 + wid * 32;
  const int qrow = q0w + l32;
  const int nkt = jX + 1;

  // ---- hoisted, kt-invariant LDS read offsets ----
  int coK[4], coVa[4], coVb[4];
#pragma unroll
  for (int st = 0; st < 4; ++st) coK[st] = (st * 32 + hi * 16) ^ rxor;
#pragma unroll
  for (int ks = 0; ks < 4; ++ks) {
    coVa[ks] = (ks * 32 + hi * 8) ^ rxor;
    coVb[ks] = (ks * 32 + 16 + hi * 8) ^ rxor;
  }
  const int rb0 = l32 * 128, rb1 = (32 + l32) * 128;

  // ---- staging geometry: chunk c = i*128+tid -> row i*16+trow ----
  const int trow = tid >> 3;  // 0..15
  const int tcol = ((((tid & 7) << 4) ^ ((trow & 7) << 4)) >> 1);  // u16 units
  const int tdst = tid << 3;  // u16 units
  const u16* kp0 = Kg + qk_base + (size_t)trow * 64 + tcol;
  const u16* kp1 = kp0 + (size_t)16 * 64;
  const u16* kp2 = kp0 + (size_t)32 * 64;
  const u16* kp3 = kp0 + (size_t)48 * 64;
  const u16* vq0 = Vtg + vt_base + (size_t)trow * 4096 + tcol;
  const u16* vq1 = vq0 + (size_t)16 * 4096;
  const u16* vq2 = vq0 + (size_t)32 * 4096;
  const u16* vq3 = vq0 + (size_t)48 * 4096;

  auto stage = [&](u16* Kd, u16* Vd) {
    gl_lds16(kp0, Kd + tdst);
    gl_lds16(kp1, Kd + 1024 + tdst);
    gl_lds16(kp2, Kd + 2048 + tdst);
    gl_lds16(kp3, Kd + 3072 + tdst);
    gl_lds16(vq0, Vd + tdst);
    gl_lds16(vq1, Vd + 1024 + tdst);
    gl_lds16(vq2, Vd + 2048 + tdst);
    gl_lds16(vq3, Vd + 3072 + tdst);
    kp0 += 4096; kp1 += 4096; kp2 += 4096; kp3 += 4096;
    vq0 += 64; vq1 += 64; vq2 += 64; vq3 += 64;
  };

  // Q fragments (B-operand): col=q(=l32), k=hi*8+j (+16*st). Pre-scaled.
  bf16x8 qb[4];
#pragma unroll
  for (int st = 0; st < 4; ++st)
    qb[st] = *(const bf16x8*)(Qg + qk_base + (size_t)qrow * 64 + st * 16 + hi * 8);

  f32x16 o0 = zero16(), o1 = zero16();
  float mrun = -3.0e38f, lrun = 0.f;

  stage(Ks[0], Vs[0]);
  __syncthreads();

  int cur = 0;
  for (int kt = 0; kt < nkt; ++kt) {
    if (kt + 1 < nkt) {
      stage(Ks[cur ^ 1], Vs[cur ^ 1]);  // prefetch; drained at end barrier
    }
    const bool diag = (kt == nkt - 1);
    const bool halfskip = diag && (wid == 0);  // upper 32 k fully masked
    const char* Kbp = (const char*)Ks[cur];
    const char* Vb = (const char*)Vs[cur];

    // ---- S^T = K . Q^T (log2-domain) ----
    f32x16 s0 = zero16(), s1 = zero16();
    __builtin_amdgcn_s_setprio(1);
#pragma unroll
    for (int st = 0; st < 4; ++st) {
      bf16x8 ka0 = *(const bf16x8*)(Kbp + rb0 + coK[st]);
      s0 = __builtin_amdgcn_mfma_f32_32x32x16_bf16(ka0, qb[st], s0, 0, 0, 0);
    }
    if (!halfskip) {
#pragma unroll
      for (int st = 0; st < 4; ++st) {
        bf16x8 ka1 = *(const bf16x8*)(Kbp + rb1 + coK[st]);
        s1 = __builtin_amdgcn_mfma_f32_32x32x16_bf16(ka1, qb[st], s1, 0, 0, 0);
      }
    }
    __builtin_amdgcn_s_setprio(0);

    // ---- causal mask: diagonal tile only ----
    if (diag) {
      const int kbase = kt * 64 + 4 * hi;
#pragma unroll
      for (int r = 0; r < 16; ++r) {
        int kpv = kbase + (r & 3) + 8 * (r >> 2);
        s0[r] = (kpv > qrow) ? -3.0e38f : s0[r];
        if (!halfskip) s1[r] = (kpv + 32 > qrow) ? -3.0e38f : s1[r];
      }
    }

    // ---- row max (lane-local tree + cross-half shfl) ----
    float m8[8];
#pragma unroll
    for (int r = 0; r < 8; ++r) {
      float v = fmaxf(s0[r], s0[r + 8]);
      if (!halfskip) v = fmaxf(v, fmaxf(s1[r], s1[r + 8]));
      m8[r] = v;
    }
    float mx = fmaxf(fmaxf(fmaxf(m8[0], m8[1]), fmaxf(m8[2], m8[3])),
                     fmaxf(fmaxf(m8[4], m8[5]), fmaxf(m8[6], m8[7])));
    mx = fmaxf(mx, __shfl_xor(mx, 32, 64));

    // ---- defer-max rescale (thr = 8 log2-units) ----
    if (__ballot(mx > mrun + 8.0f) != 0ull) {
      float mnew = fmaxf(mrun, mx);
      float al = __builtin_amdgcn_exp2f(mrun - mnew);
      o0 *= al;
      o1 *= al;
      lrun *= al;
      mrun = mnew;
    }

    // ---- exponentiate in place ----
#pragma unroll
    for (int r = 0; r < 16; ++r) {
      s0[r] = __builtin_amdgcn_exp2f(s0[r] - mrun);
      if (!halfskip) s1[r] = __builtin_amdgcn_exp2f(s1[r] - mrun);
    }

    // ---- row sum ----
    float a8[8];
#pragma unroll
    for (int r = 0; r < 8; ++r) {
      float v = s0[r] + s0[r + 8];
      if (!halfskip) v += s1[r] + s1[r + 8];
      a8[r] = v;
    }
    float rs = ((a8[0] + a8[1]) + (a8[2] + a8[3])) +
               ((a8[4] + a8[5]) + (a8[6] + a8[7]));
    rs += __shfl_xor(rs, 32, 64);
    lrun += rs;

    // ---- PV with k-permutation sigma (no cross-lane exchange) ----
    __builtin_amdgcn_s_setprio(1);
#pragma unroll
    for (int ks = 0; ks < 4; ++ks) {
      if (ks >= 2 && halfskip) continue;
      const f32x16& P = (ks >= 2) ? s1 : s0;
      const int base = (ks & 1) * 8;
      u32x4 w = { pk2(P[base + 0], P[base + 1]), pk2(P[base + 2], P[base + 3]),
                  pk2(P[base + 4], P[base + 5]), pk2(P[base + 6], P[base + 7]) };
      bf16x8 pbk = __builtin_bit_cast(bf16x8, w);
      u32x2 q0 = *(const u32x2*)(Vb + rb0 + coVa[ks]);
      u32x2 q1 = *(const u32x2*)(Vb + rb0 + coVb[ks]);
      u32x4 av = {q0[0], q0[1], q1[0], q1[1]};
      bf16x8 va0 = __builtin_bit_cast(bf16x8, av);
      o0 = __builtin_amdgcn_mfma_f32_32x32x16_bf16(va0, pbk, o0, 0, 0, 0);
      u32x2 p0 = *(const u32x2*)(Vb + rb1 + coVa[ks]);
      u32x2 p1 = *(const u32x2*)(Vb + rb1 + coVb[ks]);
      u32x4 bv = {p0[0], p0[1], p1[0], p1[1]};
      bf16x8 va1 = __builtin_bit_cast(bf16x8, bv);
      o1 = __builtin_amdgcn_mfma_f32_32x32x16_bf16(va1, pbk, o1, 0, 0, 0);
    }
    __builtin_amdgcn_s_setprio(0);

    __syncthreads();  // prefetch landed; LDS reads of cur complete
    cur ^= 1;
  }

  // ---- finalize: O^T reg r -> d = (r&3)+8*(r>>2)+4*hi (+32 for o1) ----
  float inv = 1.0f / lrun;
  u16* orow = Og + ((size_t)b * 4096 + qrow) * 768 + h * 64;
#pragma unroll
  for (int gg = 0; gg < 4; ++gg) {
    u16x4 v0, v1;
#pragma unroll
    for (int i = 0; i < 4; ++i) {
      v0[i] = f2bf(o0[4 * gg + i] * inv);
      v1[i] = f2bf(o1[4 * gg + i] * inv);
    }
    *(u16x4*)(orow + 8 * gg + 4 * hi) = v0;
    *(u16x4*)(orow + 32 + 8 * gg + 4 * hi) = v1;
  }
}

// ---------------------------------------------------------------------------
// launch
// ---------------------------------------------------------------------------
extern "C" void kernel_launch(void* const* d_in, const int* in_sizes, int n_in,
                              void* d_out, int out_size, void* d_ws, size_t ws_size,
                              hipStream_t stream) {
  const float* x = (const float*)d_in[0];
  const float* Wqkv = (const float*)d_in[1];
  const float* bqkv = (const float*)d_in[2];
  const float* Wproj = (const float*)d_in[3];
  const float* bproj = (const float*)d_in[4];
  float* out = (float*)d_out;

  char* ws = (char*)d_ws;
  u16* Xbf = (u16*)(ws + 0);            // 12,582,912
  u16* WqkvT = (u16*)(ws + 12582912);   //  3,538,944
  u16* WprojT = (u16*)(ws + 16121856);  //  1,179,648
  u16* Q = (u16*)(ws + 17301504);       // 12,582,912
  u16* K = (u16*)(ws + 29884416);       // 12,582,912
  u16* Vt = (u16*)(ws + 42467328);      // 12,582,912
  u16* O = (u16*)(ws + 55050240);       // 12,582,912

  k_cvt<<<6144, 256, 0, stream>>>(x, Xbf, 1572864);
  k_transpose_cvt<<<dim3(72, 24), dim3(32, 8), 0, stream>>>(Wqkv, WqkvT, 768, 2304);
  k_transpose_cvt<<<dim3(24, 24), dim3(32, 8), 0, stream>>>(Wproj, WprojT, 768, 768);
  k_gemm_qkv<<<dim3(18, 64), 256, 0, stream>>>(Xbf, WqkvT, bqkv, Q, K, Vt);
  k_attn<<<1536, 128, 0, stream>>>(Q, K, Vt, O);
  k_gemm_proj<<<dim3(6, 64), 256, 0, stream>>>(O, WprojT, bproj, out);
}